// Round 4
// baseline (135556.396 us; speedup 1.0000x reference)
//
#include <hip/hip_runtime.h>
#include <hip/hip_cooperative_groups.h>
#include <math.h>

namespace cg = cooperative_groups;

#define BB 32
#define SS 256
#define EE 512
#define HH 1024
#define DD 2048
#define VV 10000
#define KS 4
#define NBLK 256
#define NTHR 1024
#define NSLOT (NBLK * 32)  // 8192 fc row-slots

// NOTE: macro params must not collide with .x/.y/.z/.w member tokens!
#define DOT4(acc, q, r)                                                       \
  acc = fmaf((q).x, (r).x, acc); acc = fmaf((q).y, (r).y, acc);               \
  acc = fmaf((q).z, (r).z, acc); acc = fmaf((q).w, (r).w, acc);

// order-preserving float -> uint (monotone; bigger float => bigger uint)
__device__ __forceinline__ unsigned enc_f32(float f) {
  unsigned u = __float_as_uint(f);
  return (u & 0x80000000u) ? ~u : (u | 0x80000000u);
}

__global__ __launch_bounds__(NTHR) void k_mega(
    const int* __restrict__ x, const float* __restrict__ emb,
    const float* __restrict__ Wih_f, const float* __restrict__ Whh_f,
    const float* __restrict__ b_f,
    const float* __restrict__ Wih_b, const float* __restrict__ Whh_b,
    const float* __restrict__ b_b,
    const float* __restrict__ Wih_d, const float* __restrict__ Whh_d,
    const float* __restrict__ b_d,
    const float* __restrict__ eg, const float* __restrict__ ebt,
    const float* __restrict__ dg, const float* __restrict__ dbt,
    const float* __restrict__ fcW, const float* __restrict__ fcb,
    float* __restrict__ out,
    float* __restrict__ xeT, float* __restrict__ hfT, float* __restrict__ hbT,
    float* __restrict__ cfT, float* __restrict__ cbT, float* __restrict__ hdT,
    float* __restrict__ cdT, float* __restrict__ outT,
    unsigned long long* __restrict__ winners) {
  cg::grid_group grid = cg::this_grid();
  const int gid = blockIdx.x, tid = threadIdx.x;
  const int fl = gid * NTHR + tid;
  const int b = tid & 31, jj = (tid >> 5) & 7, ks = tid >> 8;

  __shared__ float4 red[KS - 1][8][32];              // 12 KB gates reduce
  __shared__ unsigned long long kred[32][32];        // 8 KB fc argmax reduce

  // ---------------- phase 0: embed, zero states, zero out[:,0,:] ----------
  for (int i = fl; i < SS * EE * BB; i += NBLK * NTHR) {
    int s = i / (EE * BB);
    int r = i % (EE * BB);
    int k = (r >> 7) * 4 + (r & 3);
    int b2 = (r >> 2) & 31;
    xeT[i] = emb[(size_t)x[b2 * SS + s] * EE + k];
  }
  // hfT,hbT,cfT,cbT,hdT,cdT are contiguous in ws: 393216 floats
  for (int i = fl; i < 2 * HH * BB * 2 + HH * BB * 2 + 2 * DD * BB + DD * BB;
       i += NBLK * NTHR)
    hfT[i] = 0.0f;
  for (int i = fl; i < BB * VV; i += NBLK * NTHR) {
    int b2 = i / VV, v = i % VV;
    out[(size_t)b2 * SS * VV + v] = 0.0f;
  }
  if (fl < 64) winners[fl] = 0ull;
  grid.sync();

  // ---------------- encoder: 256 steps, both directions concurrently -------
  for (int t = 0; t < SS; ++t) {
    const int dir = gid >> 7;
    const float* __restrict__ Wih = dir ? Wih_b : Wih_f;
    const float* __restrict__ Whh = dir ? Whh_b : Whh_f;
    const float* __restrict__ bias = dir ? b_b : b_f;
    float* hT = dir ? hbT : hfT;
    float* cT = dir ? cbT : cfT;
    const int s = dir ? (SS - 1 - t) : t;
    const int pin = t & 1;
    const float* __restrict__ xx = xeT + (size_t)s * EE * BB;
    const float* __restrict__ hin = hT + pin * (HH * BB);
    float* __restrict__ hout = hT + (pin ^ 1) * (HH * BB);
    const int j = (gid & 127) * 8 + jj;

    float a0, a1, a2, a3;
    if (ks == 0) {
      a0 = bias[j]; a1 = bias[HH + j]; a2 = bias[2 * HH + j]; a3 = bias[3 * HH + j];
    } else {
      a0 = a1 = a2 = a3 = 0.0f;
    }
    {  // input projection chunk
      const float4* __restrict__ w0 = (const float4*)(Wih + (size_t)j * EE);
      const float4* __restrict__ w1 = (const float4*)(Wih + (size_t)(HH + j) * EE);
      const float4* __restrict__ w2 = (const float4*)(Wih + (size_t)(2 * HH + j) * EE);
      const float4* __restrict__ w3 = (const float4*)(Wih + (size_t)(3 * HH + j) * EE);
      const float4* __restrict__ xa4 = (const float4*)xx;
      const int k4b = ks * (EE / 4 / KS), k4e = k4b + EE / 4 / KS;
#pragma unroll 4
      for (int k4 = k4b; k4 < k4e; ++k4) {
        float4 av = xa4[k4 * BB + b];
        DOT4(a0, w0[k4], av); DOT4(a1, w1[k4], av);
        DOT4(a2, w2[k4], av); DOT4(a3, w3[k4], av);
      }
    }
    {  // recurrent projection chunk
      const float4* __restrict__ w0 = (const float4*)(Whh + (size_t)j * HH);
      const float4* __restrict__ w1 = (const float4*)(Whh + (size_t)(HH + j) * HH);
      const float4* __restrict__ w2 = (const float4*)(Whh + (size_t)(2 * HH + j) * HH);
      const float4* __restrict__ w3 = (const float4*)(Whh + (size_t)(3 * HH + j) * HH);
      const float4* __restrict__ ha4 = (const float4*)hin;
      const int k4b = ks * (HH / 4 / KS), k4e = k4b + HH / 4 / KS;
#pragma unroll 4
      for (int k4 = k4b; k4 < k4e; ++k4) {
        float4 av = ha4[k4 * BB + b];
        DOT4(a0, w0[k4], av); DOT4(a1, w1[k4], av);
        DOT4(a2, w2[k4], av); DOT4(a3, w3[k4], av);
      }
    }
    if (ks) red[ks - 1][jj][b] = make_float4(a0, a1, a2, a3);
    __syncthreads();
    if (ks == 0) {
#pragma unroll
      for (int s2 = 0; s2 < KS - 1; ++s2) {
        float4 r4 = red[s2][jj][b];
        a0 += r4.x; a1 += r4.y; a2 += r4.z; a3 += r4.w;
      }
      float ig = 1.0f / (1.0f + expf(-a0));
      float fg = 1.0f / (1.0f + expf(-a1));
      float gg = tanhf(a2);
      float og = 1.0f / (1.0f + expf(-a3));
      const int idx = j * BB + b;
      float c = fmaf(fg, cT[idx], ig * gg);
      cT[idx] = c;
      hout[(j >> 2) * 128 + b * 4 + (j & 3)] = og * tanhf(c);
    }
    grid.sync();
  }

  // ---------------- encoder BN + relu -> hdT parity 0 ----------------------
  if (fl < DD * BB) {
    const int d = fl >> 5;
    const int dl = (d < HH) ? d : d - HH;
    const float* __restrict__ src = (d < HH) ? hfT : hbT;
    float v = src[(dl >> 2) * 128 + b * 4 + (dl & 3)];
    float sum = v;
    for (int m = 16; m >= 1; m >>= 1) sum += __shfl_xor(sum, m, 32);
    float mean = sum * (1.0f / BB);
    float dx = v - mean;
    float s2 = dx * dx;
    for (int m = 16; m >= 1; m >>= 1) s2 += __shfl_xor(s2, m, 32);
    float var = s2 * (1.0f / BB);
    float y = dx * (1.0f / sqrtf(var + 1e-5f)) * eg[d] + ebt[d];
    hdT[(d >> 2) * 128 + b * 4 + (d & 3)] = fmaxf(y, 0.0f);
  }
  grid.sync();

  // ---------------- decoder: 255 steps --------------------------------------
  for (int t = 0; t < SS - 1; ++t) {
    // ---- gates phase (embedding gathered directly from winner tokens) ----
    int tok;
    if (t == 0) tok = x[b * SS];
    else tok = (int)(0xFFFFFFFFu -
                     (unsigned)(winners[((t - 1) & 1) * 32 + b] & 0xFFFFFFFFull));
    const int pin = t & 1;
    const float* __restrict__ hin = hdT + pin * (DD * BB);
    float* __restrict__ hout = hdT + (pin ^ 1) * (DD * BB);
    const int j = gid * 8 + jj;

    float a0, a1, a2, a3;
    if (ks == 0) {
      a0 = b_d[j]; a1 = b_d[DD + j]; a2 = b_d[2 * DD + j]; a3 = b_d[3 * DD + j];
    } else {
      a0 = a1 = a2 = a3 = 0.0f;
    }
    {  // K = E over gathered embedding row (per-lane row: 16B gather, L2-hot)
      const float4* __restrict__ w0 = (const float4*)(Wih_d + (size_t)j * EE);
      const float4* __restrict__ w1 = (const float4*)(Wih_d + (size_t)(DD + j) * EE);
      const float4* __restrict__ w2 = (const float4*)(Wih_d + (size_t)(2 * DD + j) * EE);
      const float4* __restrict__ w3 = (const float4*)(Wih_d + (size_t)(3 * DD + j) * EE);
      const float4* __restrict__ er = (const float4*)(emb + (size_t)tok * EE);
      const int k4b = ks * (EE / 4 / KS), k4e = k4b + EE / 4 / KS;
#pragma unroll 4
      for (int k4 = k4b; k4 < k4e; ++k4) {
        float4 av = er[k4];
        DOT4(a0, w0[k4], av); DOT4(a1, w1[k4], av);
        DOT4(a2, w2[k4], av); DOT4(a3, w3[k4], av);
      }
    }
    {  // K = D over hin
      const float4* __restrict__ w0 = (const float4*)(Whh_d + (size_t)j * DD);
      const float4* __restrict__ w1 = (const float4*)(Whh_d + (size_t)(DD + j) * DD);
      const float4* __restrict__ w2 = (const float4*)(Whh_d + (size_t)(2 * DD + j) * DD);
      const float4* __restrict__ w3 = (const float4*)(Whh_d + (size_t)(3 * DD + j) * DD);
      const float4* __restrict__ ha4 = (const float4*)hin;
      const int k4b = ks * (DD / 4 / KS), k4e = k4b + DD / 4 / KS;
#pragma unroll 4
      for (int k4 = k4b; k4 < k4e; ++k4) {
        float4 av = ha4[k4 * BB + b];
        DOT4(a0, w0[k4], av); DOT4(a1, w1[k4], av);
        DOT4(a2, w2[k4], av); DOT4(a3, w3[k4], av);
      }
    }
    if (ks) red[ks - 1][jj][b] = make_float4(a0, a1, a2, a3);
    __syncthreads();
    if (ks == 0) {
#pragma unroll
      for (int s2 = 0; s2 < KS - 1; ++s2) {
        float4 r4 = red[s2][jj][b];
        a0 += r4.x; a1 += r4.y; a2 += r4.z; a3 += r4.w;
      }
      float ig = 1.0f / (1.0f + expf(-a0));
      float fg = 1.0f / (1.0f + expf(-a1));
      float gg = tanhf(a2);
      float og = 1.0f / (1.0f + expf(-a3));
      const int idx = j * BB + b;
      float c = fmaf(fg, cdT[idx], ig * gg);
      cdT[idx] = c;
      float h = og * tanhf(c);
      hout[(j >> 2) * 128 + b * 4 + (j & 3)] = h;
      // fused BN over batch + relu
      float sum = h;
      for (int m = 16; m >= 1; m >>= 1) sum += __shfl_xor(sum, m, 32);
      float mean = sum * (1.0f / BB);
      float dx = h - mean;
      float s2v = dx * dx;
      for (int m = 16; m >= 1; m >>= 1) s2v += __shfl_xor(s2v, m, 32);
      float var = s2v * (1.0f / BB);
      float y = dx * (1.0f / sqrtf(var + 1e-5f)) * dg[j] + dbt[j];
      outT[(j >> 2) * 128 + b * 4 + (j & 3)] = fmaxf(y, 0.0f);
    }
    grid.sync();

    // ---- fc phase + fused argmax (keys -> block reduce -> atomicMax) ----
    {
      const int slot_l = tid >> 5;                 // 0..31
      const int slot = gid * 32 + slot_l;          // 0..8191
      const int r0 = (slot * VV) >> 13;            // slot*10000/8192
      const int r1 = ((slot + 1) * VV) >> 13;
      unsigned long long bestkey = 0ull;
      const float4* __restrict__ xa4 = (const float4*)outT;
      const size_t obase = (size_t)b * SS * VV + (size_t)(t + 1) * VV;
      for (int v = r0; v < r1; ++v) {
        float acc = fcb[v];
        const float4* __restrict__ w = (const float4*)(fcW + (size_t)v * DD);
#pragma unroll 8
        for (int k4 = 0; k4 < DD / 4; ++k4) {
          float4 av = xa4[k4 * BB + b];
          DOT4(acc, w[k4], av);
        }
        out[obase + v] = acc;
        unsigned long long key =
            ((unsigned long long)enc_f32(acc) << 32) | (0xFFFFFFFFu - (unsigned)v);
        if (key > bestkey) bestkey = key;
      }
      kred[slot_l][b] = bestkey;
      __syncthreads();
#pragma unroll
      for (int s2 = 16; s2 >= 1; s2 >>= 1) {
        if (slot_l < s2) {
          unsigned long long o = kred[slot_l + s2][b];
          if (o > kred[slot_l][b]) kred[slot_l][b] = o;
        }
        __syncthreads();
      }
      if (tid < 32) atomicMax(&winners[(t & 1) * 32 + tid], kred[0][tid]);
      // reset the buffer fc(t+1) will use; it was last read by gates(t)
      if (gid == 0 && tid >= 32 && tid < 64)
        winners[((t + 1) & 1) * 32 + (tid - 32)] = 0ull;
    }
    grid.sync();
  }
}

extern "C" void kernel_launch(void* const* d_in, const int* in_sizes, int n_in,
                              void* d_out, int out_size, void* d_ws, size_t ws_size,
                              hipStream_t stream) {
  const int*   x         = (const int*)d_in[0];
  const float* emb       = (const float*)d_in[1];
  const float* Wih_f     = (const float*)d_in[2];
  const float* Whh_f     = (const float*)d_in[3];
  const float* b_f       = (const float*)d_in[4];
  const float* Wih_b     = (const float*)d_in[5];
  const float* Whh_b     = (const float*)d_in[6];
  const float* b_b       = (const float*)d_in[7];
  const float* Wih_d     = (const float*)d_in[8];
  const float* Whh_d     = (const float*)d_in[9];
  const float* b_d       = (const float*)d_in[10];
  const float* enc_gamma = (const float*)d_in[11];
  const float* enc_beta  = (const float*)d_in[12];
  const float* dec_gamma = (const float*)d_in[13];
  const float* dec_beta  = (const float*)d_in[14];
  const float* fcW       = (const float*)d_in[15];
  const float* fcb       = (const float*)d_in[16];
  float* out = (float*)d_out;
  float* ws  = (float*)d_ws;

  size_t off = 0;
  float* xeT = ws + off; off += (size_t)SS * EE * BB;   // 4,194,304
  float* hfT = ws + off; off += 2 * HH * BB;            // contiguous zero block
  float* hbT = ws + off; off += 2 * HH * BB;
  float* cfT = ws + off; off += HH * BB;
  float* cbT = ws + off; off += HH * BB;
  float* hdT = ws + off; off += 2 * DD * BB;
  float* cdT = ws + off; off += DD * BB;
  float* outT = ws + off; off += DD * BB;
  unsigned long long* winners = (unsigned long long*)(ws + off); off += 128;

  void* args[] = {
      (void*)&x, (void*)&emb,
      (void*)&Wih_f, (void*)&Whh_f, (void*)&b_f,
      (void*)&Wih_b, (void*)&Whh_b, (void*)&b_b,
      (void*)&Wih_d, (void*)&Whh_d, (void*)&b_d,
      (void*)&enc_gamma, (void*)&enc_beta, (void*)&dec_gamma, (void*)&dec_beta,
      (void*)&fcW, (void*)&fcb, (void*)&out,
      (void*)&xeT, (void*)&hfT, (void*)&hbT, (void*)&cfT, (void*)&cbT,
      (void*)&hdT, (void*)&cdT, (void*)&outT, (void*)&winners};

  hipLaunchCooperativeKernel((const void*)k_mega, dim3(NBLK), dim3(NTHR), args,
                             0, stream);
}

// Round 5
// 111116.553 us; speedup vs baseline: 1.2199x; 1.2199x over previous
//
#include <hip/hip_runtime.h>
#include <math.h>

#define BB 32
#define SS 256
#define EE 512
#define HH 1024
#define DD 2048
#define VV 10000

// ---------------------------------------------------------------------------
// ws layout (floats). Activation tensors interleaved [K/4][B][4] so a thread's
// activation load is one coalesced float4.
//   xeT : [S][E/4][B][4]  encoder inputs          (4,194,304)
//   hfT : [2][H/4][B][4]  fwd hidden ping-pong    (65,536)
//   hbT : [2][H/4][B][4]                          (65,536)
//   cfT : [H][B]                                  (32,768)
//   cbT : [H][B]                                  (32,768)
//   hdT : [2][D/4][B][4]  decoder hidden          (131,072)
//   cdT : [D][B]                                  (65,536)
//   outT: [D/4][B][4]     relu(bn(h))             (65,536)
//   winners: u64[2][32]   per-step argmax keys (double-buffered by parity)
//
// GEMV structure (all 3 big kernels): thread = (weight-row, batch-lane b).
// 4 split fp32 acc chains per thread + unroll 8 -> ~8 independent weight-load
// streams in flight (fixes the 190 GB/s latency-bound streaming of round 4).
// ---------------------------------------------------------------------------

#define DOT4S(q, r)                                                           \
  c0 = fmaf((q).x, (r).x, c0); c1 = fmaf((q).y, (r).y, c1);                   \
  c2 = fmaf((q).z, (r).z, c2); c3 = fmaf((q).w, (r).w, c3);

// order-preserving float -> uint (monotone)
__device__ __forceinline__ unsigned enc_f32(float f) {
  unsigned u = __float_as_uint(f);
  return (u & 0x80000000u) ? ~u : (u | 0x80000000u);
}

__global__ __launch_bounds__(256) void k_zero(float* __restrict__ p, int n) {
  int i = blockIdx.x * 256 + threadIdx.x;
  if (i < n) p[i] = 0.0f;
}

// zero d_out[:, 0, :] and the winners table
__global__ __launch_bounds__(256) void k_out0(float* __restrict__ out,
                                              unsigned long long* __restrict__ winners) {
  int i = blockIdx.x * 256 + threadIdx.x;
  if (i < BB * VV) {
    int b = i / VV, v = i % VV;
    out[(size_t)b * SS * VV + v] = 0.0f;
  }
  if (i < 64) winners[i] = 0ull;
}

// xeT[s][k4][b][c] = emb[x[b][s]][4*k4+c]
__global__ __launch_bounds__(256) void k_embed(const int* __restrict__ x,
                                               const float* __restrict__ emb,
                                               float* __restrict__ xeT) {
  int i = blockIdx.x * 256 + threadIdx.x;
  int s = i / (EE * BB);
  int r = i % (EE * BB);
  int k = (r >> 7) * 4 + (r & 3);
  int b = (r >> 2) & 31;
  xeT[i] = emb[(size_t)x[b * SS + s] * EE + k];
}

// One encoder step, both directions. Block: 2 j x 4 gates x 32 b = 256 thr.
// grid = dim3(HH/2, 2). One weight row per thread.
__global__ __launch_bounds__(256, 4) void k_enc_step(
    int t, const float* __restrict__ xeT,
    float* __restrict__ hfT, float* __restrict__ cfT,
    float* __restrict__ hbT, float* __restrict__ cbT,
    const float* __restrict__ Wih_f, const float* __restrict__ Whh_f,
    const float* __restrict__ b_f,
    const float* __restrict__ Wih_b, const float* __restrict__ Whh_b,
    const float* __restrict__ b_b) {
  const int dir = blockIdx.y;
  const float* __restrict__ Wih  = dir ? Wih_b : Wih_f;
  const float* __restrict__ Whh  = dir ? Whh_b : Whh_f;
  const float* __restrict__ bias = dir ? b_b : b_f;
  float* hT = dir ? hbT : hfT;
  float* cT = dir ? cbT : cfT;
  const int sstep = dir ? (SS - 1 - t) : t;
  const int pin = t & 1;
  const float4* __restrict__ xa4 =
      (const float4*)(xeT + (size_t)sstep * EE * BB);
  const float4* __restrict__ ha4 = (const float4*)(hT + pin * (HH * BB));
  float* __restrict__ hout = hT + (pin ^ 1) * (HH * BB);

  const int tid = threadIdx.x;
  const int b = tid & 31, sl = tid >> 5;
  const int jj = sl & 1, g = sl >> 1;
  const int j = blockIdx.x * 2 + jj;
  const int row = g * HH + j;

  float c0 = 0.f, c1 = 0.f, c2 = 0.f, c3 = 0.f;
  {  // recurrent projection, K = H
    const float4* __restrict__ w = (const float4*)(Whh + (size_t)row * HH);
#pragma unroll 8
    for (int k4 = 0; k4 < HH / 4; ++k4) {
      float4 q = w[k4];
      float4 av = ha4[k4 * BB + b];
      DOT4S(q, av);
    }
  }
  {  // input projection, K = E
    const float4* __restrict__ w = (const float4*)(Wih + (size_t)row * EE);
#pragma unroll 8
    for (int k4 = 0; k4 < EE / 4; ++k4) {
      float4 q = w[k4];
      float4 av = xa4[k4 * BB + b];
      DOT4S(q, av);
    }
  }
  float a = bias[row] + ((c0 + c1) + (c2 + c3));

  __shared__ float sred[4][2][32];
  sred[g][jj][b] = a;
  __syncthreads();
  if (g == 0) {
    float ai = sred[0][jj][b], af = sred[1][jj][b];
    float ag = sred[2][jj][b], ao = sred[3][jj][b];
    float ig = 1.0f / (1.0f + expf(-ai));
    float fg = 1.0f / (1.0f + expf(-af));
    float gg = tanhf(ag);
    float og = 1.0f / (1.0f + expf(-ao));
    const int idx = j * BB + b;
    float c = fmaf(fg, cT[idx], ig * gg);
    cT[idx] = c;
    hout[(j >> 2) * 128 + b * 4 + (j & 3)] = og * tanhf(c);
  }
}

// hn = relu(bn(concat(hf, hb))) -> hdT parity 0 (interleaved layout)
__global__ __launch_bounds__(256) void k_enc_bn(
    const float* __restrict__ hfT, const float* __restrict__ hbT,
    const float* __restrict__ gamma, const float* __restrict__ beta,
    float* __restrict__ hdT) {
  const int d = blockIdx.x * 8 + (threadIdx.x >> 5);
  const int b = threadIdx.x & 31;
  const int dl = (d < HH) ? d : d - HH;
  const float* __restrict__ src = (d < HH) ? hfT : hbT;
  float v = src[(dl >> 2) * 128 + b * 4 + (dl & 3)];
  float sum = v;
  for (int m = 16; m >= 1; m >>= 1) sum += __shfl_xor(sum, m, 32);
  float mean = sum * (1.0f / BB);
  float dx = v - mean;
  float s2 = dx * dx;
  for (int m = 16; m >= 1; m >>= 1) s2 += __shfl_xor(s2, m, 32);
  float var = s2 * (1.0f / BB);
  float y = dx * (1.0f / sqrtf(var + 1e-5f)) * gamma[d] + beta[d];
  hdT[(d >> 2) * 128 + b * 4 + (d & 3)] = fmaxf(y, 0.0f);
}

// Decoder gates + cell + fused BN/relu + fused embedding gather.
// Block: 2 j x 4 gates x 32 b = 256 thr; grid = DD/2 = 1024 blocks.
__global__ __launch_bounds__(256, 4) void k_dec_gates(
    int t, const int* __restrict__ x, const float* __restrict__ emb,
    float* __restrict__ hdT, float* __restrict__ cdT, float* __restrict__ outT,
    const float* __restrict__ Wih, const float* __restrict__ Whh,
    const float* __restrict__ bias,
    const float* __restrict__ gamma, const float* __restrict__ beta,
    const unsigned long long* __restrict__ winners) {
  const int tid = threadIdx.x;
  const int b = tid & 31, sl = tid >> 5;
  const int jj = sl & 1, g = sl >> 1;
  const int j = blockIdx.x * 2 + jj;
  const int row = g * DD + j;
  const int pin = t & 1;
  const float4* __restrict__ ha4 = (const float4*)(hdT + pin * (DD * BB));
  float* __restrict__ hout = hdT + (pin ^ 1) * (DD * BB);

  const int tok =
      (t == 0) ? x[b * SS]
               : (int)(0xFFFFFFFFu -
                       (unsigned)(winners[((t - 1) & 1) * 32 + b] &
                                  0xFFFFFFFFull));

  float c0 = 0.f, c1 = 0.f, c2 = 0.f, c3 = 0.f;
  {  // recurrent projection, K = D
    const float4* __restrict__ w = (const float4*)(Whh + (size_t)row * DD);
#pragma unroll 8
    for (int k4 = 0; k4 < DD / 4; ++k4) {
      float4 q = w[k4];
      float4 av = ha4[k4 * BB + b];
      DOT4S(q, av);
    }
  }
  {  // input projection over gathered embedding row, K = E
    const float4* __restrict__ w = (const float4*)(Wih + (size_t)row * EE);
    const float4* __restrict__ er = (const float4*)(emb + (size_t)tok * EE);
#pragma unroll 8
    for (int k4 = 0; k4 < EE / 4; ++k4) {
      float4 q = w[k4];
      float4 av = er[k4];
      DOT4S(q, av);
    }
  }
  float a = bias[row] + ((c0 + c1) + (c2 + c3));

  __shared__ float sred[4][2][32];
  sred[g][jj][b] = a;
  __syncthreads();
  if (g == 0) {
    float ai = sred[0][jj][b], af = sred[1][jj][b];
    float ag = sred[2][jj][b], ao = sred[3][jj][b];
    float ig = 1.0f / (1.0f + expf(-ai));
    float fg = 1.0f / (1.0f + expf(-af));
    float gg = tanhf(ag);
    float og = 1.0f / (1.0f + expf(-ao));
    const int idx = j * BB + b;
    float c = fmaf(fg, cdT[idx], ig * gg);
    cdT[idx] = c;
    float h = og * tanhf(c);
    hout[(j >> 2) * 128 + b * 4 + (j & 3)] = h;
    // fused BN over batch (32 lanes share feature j) + relu
    float sum = h;
    for (int m = 16; m >= 1; m >>= 1) sum += __shfl_xor(sum, m, 32);
    float mean = sum * (1.0f / BB);
    float dx = h - mean;
    float s2 = dx * dx;
    for (int m = 16; m >= 1; m >>= 1) s2 += __shfl_xor(s2, m, 32);
    float var = s2 * (1.0f / BB);
    float y = dx * (1.0f / sqrtf(var + 1e-5f)) * gamma[j] + beta[j];
    outT[(j >> 2) * 128 + b * 4 + (j & 3)] = fmaxf(y, 0.0f);
  }
}

// fc + fused argmax. Block: 8 rows x 32 b = 256 thr; grid = VV/8 = 1250.
__global__ __launch_bounds__(256, 4) void k_fc(
    int t, const float* __restrict__ outT, const float* __restrict__ fcW,
    const float* __restrict__ fcb, float* __restrict__ out,
    unsigned long long* __restrict__ winners) {
  const int tid = threadIdx.x;
  const int b = tid & 31, sl = tid >> 5;
  const int v = blockIdx.x * 8 + sl;
  const float4* __restrict__ xa4 = (const float4*)outT;
  const float4* __restrict__ w = (const float4*)(fcW + (size_t)v * DD);
  float c0 = 0.f, c1 = 0.f, c2 = 0.f, c3 = 0.f;
#pragma unroll 8
  for (int k4 = 0; k4 < DD / 4; ++k4) {
    float4 q = w[k4];
    float4 av = xa4[k4 * BB + b];
    DOT4S(q, av);
  }
  float acc = fcb[v] + ((c0 + c1) + (c2 + c3));
  out[(size_t)b * SS * VV + (size_t)(t + 1) * VV + v] = acc;

  // fused argmax: order-preserving key, block reduce, one atomicMax per b
  __shared__ unsigned long long kred[8][32];
  unsigned long long key =
      ((unsigned long long)enc_f32(acc) << 32) | (0xFFFFFFFFu - (unsigned)v);
  kred[sl][b] = key;
  __syncthreads();
  if (sl < 4) {
    unsigned long long o = kred[sl + 4][b];
    if (o > kred[sl][b]) kred[sl][b] = o;
  }
  __syncthreads();
  if (sl < 2) {
    unsigned long long o = kred[sl + 2][b];
    if (o > kred[sl][b]) kred[sl][b] = o;
  }
  __syncthreads();
  if (sl == 0) {
    unsigned long long o = kred[1][b];
    if (o > kred[0][b]) kred[0][b] = o;
    atomicMax(&winners[(t & 1) * 32 + b], kred[0][b]);
  }
  // reset the other buffer for fc(t+1); nobody touches it this dispatch
  if (blockIdx.x == 0 && sl == 2)
    winners[((t + 1) & 1) * 32 + b] = 0ull;
}

extern "C" void kernel_launch(void* const* d_in, const int* in_sizes, int n_in,
                              void* d_out, int out_size, void* d_ws, size_t ws_size,
                              hipStream_t stream) {
  const int*   x         = (const int*)d_in[0];
  const float* emb       = (const float*)d_in[1];
  const float* Wih_f     = (const float*)d_in[2];
  const float* Whh_f     = (const float*)d_in[3];
  const float* b_f       = (const float*)d_in[4];
  const float* Wih_b     = (const float*)d_in[5];
  const float* Whh_b     = (const float*)d_in[6];
  const float* b_b       = (const float*)d_in[7];
  const float* Wih_d     = (const float*)d_in[8];
  const float* Whh_d     = (const float*)d_in[9];
  const float* b_d       = (const float*)d_in[10];
  const float* enc_gamma = (const float*)d_in[11];
  const float* enc_beta  = (const float*)d_in[12];
  const float* dec_gamma = (const float*)d_in[13];
  const float* dec_beta  = (const float*)d_in[14];
  const float* fcW       = (const float*)d_in[15];
  const float* fcb       = (const float*)d_in[16];
  float* out = (float*)d_out;
  float* ws  = (float*)d_ws;

  size_t off = 0;
  float* xeT = ws + off; off += (size_t)SS * EE * BB;
  float* hfT = ws + off; off += 2 * HH * BB;   // start of contiguous zero block
  float* hbT = ws + off; off += 2 * HH * BB;
  float* cfT = ws + off; off += HH * BB;
  float* cbT = ws + off; off += HH * BB;
  float* hdT = ws + off; off += 2 * DD * BB;
  float* cdT = ws + off; off += DD * BB;
  float* outT = ws + off; off += DD * BB;
  unsigned long long* winners = (unsigned long long*)(ws + off); off += 128;

  // zero h/c states (contiguous: hfT..cdT = 393216 floats)
  const int nz = 2 * HH * BB * 2 + HH * BB * 2 + 2 * DD * BB + DD * BB;
  k_zero<<<(nz + 255) / 256, 256, 0, stream>>>(hfT, nz);
  k_out0<<<(BB * VV + 255) / 256, 256, 0, stream>>>(out, winners);
  k_embed<<<(SS * EE * BB) / 256, 256, 0, stream>>>(x, emb, xeT);

  for (int t = 0; t < SS; ++t)
    k_enc_step<<<dim3(HH / 2, 2), 256, 0, stream>>>(t, xeT, hfT, cfT, hbT, cbT,
                                                    Wih_f, Whh_f, b_f,
                                                    Wih_b, Whh_b, b_b);

  k_enc_bn<<<DD / 8, 256, 0, stream>>>(hfT, hbT, enc_gamma, enc_beta, hdT);

  for (int t = 0; t < SS - 1; ++t) {
    k_dec_gates<<<DD / 2, 256, 0, stream>>>(t, x, emb, hdT, cdT, outT,
                                            Wih_d, Whh_d, b_d,
                                            dec_gamma, dec_beta, winners);
    k_fc<<<VV / 8, 256, 0, stream>>>(t, outT, fcW, fcb, out, winners);
  }
}

// Round 6
// 37200.000 us; speedup vs baseline: 3.6440x; 2.9870x over previous
//
#include <hip/hip_runtime.h>
#include <math.h>

#define BB 32
#define SS 256
#define EE 512
#define HH 1024
#define DD 2048
#define VV 10000

// ---------------------------------------------------------------------------
// Activation layout (ws): interleaved [k/4][b][4] floats, so f4-slot idx of a
// chunk maps to (k4 = idx>>5, b = idx&31) and chunk copies are LINEAR.
//
// Big kernels: skinny GEMM, block = 512 thr = 16 slots x 32 b, 32 rows/block,
// K-chunks of 128 double-buffered in LDS. Staging: per-lane coalesced float4
// (1KB/instr unique) issued EARLY, ds_write LATE (T14) -> latency hidden under
// the FMA phase. Inner loop: W via LDS broadcast (free), act via contiguous
// ds_read_b128, 8 FMA / k4 -> VALU-bound.
// Row mapping: block owns all 4 gates of 8 cells -> cell update fused.
// ---------------------------------------------------------------------------

#define DOT4A(acc, q, r)                                                      \
  acc = fmaf((q).x, (r).x, acc); acc = fmaf((q).y, (r).y, acc);               \
  acc = fmaf((q).z, (r).z, acc); acc = fmaf((q).w, (r).w, acc);

__device__ __forceinline__ unsigned enc_f32(float f) {
  unsigned u = __float_as_uint(f);
  return (u & 0x80000000u) ? ~u : (u | 0x80000000u);
}
__device__ __forceinline__ float sigm(float v) {
  return 1.0f / (1.0f + expf(-v));
}

__global__ __launch_bounds__(256) void k_zero(float* __restrict__ p, int n) {
  int i = blockIdx.x * 256 + threadIdx.x;
  if (i < n) p[i] = 0.0f;
}

__global__ __launch_bounds__(256) void k_out0(float* __restrict__ out,
                                              unsigned long long* __restrict__ winners) {
  int i = blockIdx.x * 256 + threadIdx.x;
  if (i < BB * VV) {
    int b = i / VV, v = i % VV;
    out[(size_t)b * SS * VV + v] = 0.0f;
  }
  if (i < 64) winners[i] = 0ull;
}

// xeT[s][k4][b][c] = emb[x[b][s]][4*k4+c]
__global__ __launch_bounds__(256) void k_embed(const int* __restrict__ x,
                                               const float* __restrict__ emb,
                                               float* __restrict__ xeT) {
  int i = blockIdx.x * 256 + threadIdx.x;
  int s = i / (EE * BB);
  int r = i % (EE * BB);
  int k = (r >> 7) * 4 + (r & 3);
  int b = (r >> 2) & 31;
  xeT[i] = emb[(size_t)x[b * SS + s] * EE + k];
}

// ---------------- encoder step (both dirs), fused LSTM cell -----------------
// grid 256: blk<128 fwd, else bwd. Block: cells jb..jb+7, rows = 4 gates x 8.
__global__ __launch_bounds__(512, 4) void k_enc_step(
    int t, const float* __restrict__ xeT,
    float* __restrict__ hfT, float* __restrict__ cfT,
    float* __restrict__ hbT, float* __restrict__ cbT,
    const float* __restrict__ Wih_f, const float* __restrict__ Whh_f,
    const float* __restrict__ b_f,
    const float* __restrict__ Wih_b, const float* __restrict__ Whh_b,
    const float* __restrict__ b_b) {
  __shared__ float wlds[2][32][128];
  __shared__ float alds[2][4096];
  __shared__ float sred[32][32];

  const int tid = threadIdx.x;
  const int b = tid & 31, slot = tid >> 5;
  const int dir = blockIdx.x >> 7;
  const int jb = (blockIdx.x & 127) * 8;
  const float* __restrict__ Wih = dir ? Wih_b : Wih_f;
  const float* __restrict__ Whh = dir ? Whh_b : Whh_f;
  const float* __restrict__ bias = dir ? b_b : b_f;
  float* hT = dir ? hbT : hfT;
  float* cT = dir ? cbT : cfT;
  const int s = dir ? (SS - 1 - t) : t;
  const int pin = t & 1;
  const float4* __restrict__ hin4 = (const float4*)(hT + pin * (HH * BB));
  const float4* __restrict__ xs4 = (const float4*)(xeT + (size_t)s * EE * BB);
  float* __restrict__ hout = hT + (pin ^ 1) * (HH * BB);

  const int r0 = slot * 2, r1 = r0 + 1;
  const int NC = 12;  // 8 h-chunks (K=1024) + 4 x-chunks (K=512)

  auto wsrc = [&](int cc, int idx) -> float4 {
    int lrow = idx >> 5, k4 = idx & 31;
    int grow = (lrow >> 3) * HH + jb + (lrow & 7);
    return (cc < 8)
               ? ((const float4*)(Whh + (size_t)grow * HH))[cc * 32 + k4]
               : ((const float4*)(Wih + (size_t)grow * EE))[(cc - 8) * 32 + k4];
  };
  auto asrc = [&](int cc, int idx) -> float4 {
    return (cc < 8) ? hin4[cc * 1024 + idx] : xs4[(cc - 8) * 1024 + idx];
  };

  {  // prologue: stage chunk 0
    float4 w0 = wsrc(0, tid), w1 = wsrc(0, 512 + tid);
    float4 a0 = asrc(0, tid), a1 = asrc(0, 512 + tid);
    float4* wd = (float4*)&wlds[0][0][0];
    float4* ad = (float4*)&alds[0][0];
    wd[tid] = w0; wd[512 + tid] = w1;
    ad[tid] = a0; ad[512 + tid] = a1;
  }
  __syncthreads();

  float c0 = 0.f, c1 = 0.f;
  for (int cc = 0; cc < NC; ++cc) {
    const int cb = cc & 1;
    float4 pw0, pw1, pa0, pa1;
    const bool pref = (cc + 1 < NC);
    if (pref) {  // issue next-chunk loads early (hide under FMAs)
      pw0 = wsrc(cc + 1, tid); pw1 = wsrc(cc + 1, 512 + tid);
      pa0 = asrc(cc + 1, tid); pa1 = asrc(cc + 1, 512 + tid);
    }
#pragma unroll 8
    for (int k4 = 0; k4 < 32; ++k4) {
      float4 a4 = *(const float4*)&alds[cb][(k4 * 32 + b) * 4];
      float4 w0 = *(const float4*)&wlds[cb][r0][k4 * 4];
      float4 w1 = *(const float4*)&wlds[cb][r1][k4 * 4];
      DOT4A(c0, w0, a4);
      DOT4A(c1, w1, a4);
    }
    __syncthreads();
    if (pref) {
      float4* wd = (float4*)&wlds[cb ^ 1][0][0];
      float4* ad = (float4*)&alds[cb ^ 1][0];
      wd[tid] = pw0; wd[512 + tid] = pw1;
      ad[tid] = pa0; ad[512 + tid] = pa1;
    }
    __syncthreads();
  }

  sred[r0][b] = c0 + bias[(r0 >> 3) * HH + jb + (r0 & 7)];
  sred[r1][b] = c1 + bias[(r1 >> 3) * HH + jb + (r1 & 7)];
  __syncthreads();
  if (tid < 256) {
    const int c = tid >> 5;  // cell 0..7
    float ai = sred[c][b], af = sred[8 + c][b];
    float ag = sred[16 + c][b], ao = sred[24 + c][b];
    const int j = jb + c;
    const int idx = j * BB + b;
    float cv = fmaf(sigm(af), cT[idx], sigm(ai) * tanhf(ag));
    cT[idx] = cv;
    hout[(j >> 2) * 128 + b * 4 + (j & 3)] = sigm(ao) * tanhf(cv);
  }
}

// hn = relu(bn(concat(hf, hb))) -> hdT parity 0
__global__ __launch_bounds__(256) void k_enc_bn(
    const float* __restrict__ hfT, const float* __restrict__ hbT,
    const float* __restrict__ gamma, const float* __restrict__ beta,
    float* __restrict__ hdT) {
  const int d = blockIdx.x * 8 + (threadIdx.x >> 5);
  const int b = threadIdx.x & 31;
  const int dl = (d < HH) ? d : d - HH;
  const float* __restrict__ src = (d < HH) ? hfT : hbT;
  float v = src[(dl >> 2) * 128 + b * 4 + (dl & 3)];
  float sum = v;
  for (int m = 16; m >= 1; m >>= 1) sum += __shfl_xor(sum, m, 32);
  float mean = sum * (1.0f / BB);
  float dx = v - mean;
  float s2 = dx * dx;
  for (int m = 16; m >= 1; m >>= 1) s2 += __shfl_xor(s2, m, 32);
  float var = s2 * (1.0f / BB);
  float y = dx * (1.0f / sqrtf(var + 1e-5f)) * gamma[d] + beta[d];
  hdT[(d >> 2) * 128 + b * 4 + (d & 3)] = fmaxf(y, 0.0f);
}

// ---------------- decoder gates + fused cell + BN + emb gather --------------
// grid 256 blocks: cells jb..jb+7.
__global__ __launch_bounds__(512, 4) void k_dec_gates(
    int t, const int* __restrict__ x, const float* __restrict__ emb,
    float* __restrict__ hdT, float* __restrict__ cdT, float* __restrict__ outT,
    const float* __restrict__ Wih, const float* __restrict__ Whh,
    const float* __restrict__ bias,
    const float* __restrict__ gamma, const float* __restrict__ beta,
    const unsigned long long* __restrict__ winners) {
  __shared__ float wlds[2][32][128];
  __shared__ float alds[2][4096];
  __shared__ float sred[32][32];
  __shared__ int stoks[32];

  const int tid = threadIdx.x;
  const int b = tid & 31, slot = tid >> 5;
  const int jb = blockIdx.x * 8;
  const int pin = t & 1;
  const float4* __restrict__ hin4 = (const float4*)(hdT + pin * (DD * BB));
  float* __restrict__ hout = hdT + (pin ^ 1) * (DD * BB);

  if (tid < 32) {
    stoks[tid] = (t == 0)
                     ? x[tid * SS]
                     : (int)(0xFFFFFFFFu -
                             (unsigned)(winners[((t - 1) & 1) * 32 + tid] &
                                        0xFFFFFFFFull));
  }

  const int r0 = slot * 2, r1 = r0 + 1;
  const int NC = 20;  // 16 h-chunks (K=2048) + 4 emb-chunks (K=512)

  auto wsrc = [&](int cc, int idx) -> float4 {
    int lrow = idx >> 5, k4 = idx & 31;
    int grow = (lrow >> 3) * DD + jb + (lrow & 7);
    return (cc < 16)
               ? ((const float4*)(Whh + (size_t)grow * DD))[cc * 32 + k4]
               : ((const float4*)(Wih + (size_t)grow * EE))[(cc - 16) * 32 + k4];
  };
  auto asrc = [&](int cc, int idx) -> float4 {
    if (cc < 16) return hin4[cc * 1024 + idx];
    return *(const float4*)(emb + (size_t)stoks[idx & 31] * EE +
                            (cc - 16) * 128 + ((idx >> 5) << 2));
  };

  {  // prologue: chunk 0 (h-part; stoks not needed yet)
    float4 w0 = wsrc(0, tid), w1 = wsrc(0, 512 + tid);
    float4 a0 = asrc(0, tid), a1 = asrc(0, 512 + tid);
    float4* wd = (float4*)&wlds[0][0][0];
    float4* ad = (float4*)&alds[0][0];
    wd[tid] = w0; wd[512 + tid] = w1;
    ad[tid] = a0; ad[512 + tid] = a1;
  }
  __syncthreads();

  float c0 = 0.f, c1 = 0.f;
  for (int cc = 0; cc < NC; ++cc) {
    const int cb = cc & 1;
    float4 pw0, pw1, pa0, pa1;
    const bool pref = (cc + 1 < NC);
    if (pref) {
      pw0 = wsrc(cc + 1, tid); pw1 = wsrc(cc + 1, 512 + tid);
      pa0 = asrc(cc + 1, tid); pa1 = asrc(cc + 1, 512 + tid);
    }
#pragma unroll 8
    for (int k4 = 0; k4 < 32; ++k4) {
      float4 a4 = *(const float4*)&alds[cb][(k4 * 32 + b) * 4];
      float4 w0 = *(const float4*)&wlds[cb][r0][k4 * 4];
      float4 w1 = *(const float4*)&wlds[cb][r1][k4 * 4];
      DOT4A(c0, w0, a4);
      DOT4A(c1, w1, a4);
    }
    __syncthreads();
    if (pref) {
      float4* wd = (float4*)&wlds[cb ^ 1][0][0];
      float4* ad = (float4*)&alds[cb ^ 1][0];
      wd[tid] = pw0; wd[512 + tid] = pw1;
      ad[tid] = pa0; ad[512 + tid] = pa1;
    }
    __syncthreads();
  }

  sred[r0][b] = c0 + bias[(r0 >> 3) * DD + jb + (r0 & 7)];
  sred[r1][b] = c1 + bias[(r1 >> 3) * DD + jb + (r1 & 7)];
  __syncthreads();
  if (tid < 256) {
    const int c = tid >> 5;
    float ai = sred[c][b], af = sred[8 + c][b];
    float ag = sred[16 + c][b], ao = sred[24 + c][b];
    const int j = jb + c;
    const int idx = j * BB + b;
    float cv = fmaf(sigm(af), cdT[idx], sigm(ai) * tanhf(ag));
    cdT[idx] = cv;
    float h = sigm(ao) * tanhf(cv);
    hout[(j >> 2) * 128 + b * 4 + (j & 3)] = h;
    // fused BN over batch + relu
    float sum = h;
    for (int m = 16; m >= 1; m >>= 1) sum += __shfl_xor(sum, m, 32);
    float mean = sum * (1.0f / BB);
    float dx = h - mean;
    float s2 = dx * dx;
    for (int m = 16; m >= 1; m >>= 1) s2 += __shfl_xor(s2, m, 32);
    float var = s2 * (1.0f / BB);
    float y = dx * (1.0f / sqrtf(var + 1e-5f)) * gamma[j] + beta[j];
    outT[(j >> 2) * 128 + b * 4 + (j & 3)] = fmaxf(y, 0.0f);
  }
}

// ---------------- fc + fused argmax ------------------------------------------
// grid 313 blocks x 32 rows (last block partial, clamped).
__global__ __launch_bounds__(512, 4) void k_fc(
    int t, const float* __restrict__ outT, const float* __restrict__ fcW,
    const float* __restrict__ fcb, float* __restrict__ out,
    unsigned long long* __restrict__ winners) {
  __shared__ float wlds[2][32][128];
  __shared__ float alds[2][4096];
  __shared__ unsigned long long kred[16][32];

  const int tid = threadIdx.x;
  const int b = tid & 31, slot = tid >> 5;
  const int vb = blockIdx.x * 32;
  const float4* __restrict__ xa4 = (const float4*)outT;

  const int r0 = slot * 2, r1 = r0 + 1;
  const int NC = 16;  // K = 2048

  auto wsrc = [&](int cc, int idx) -> float4 {
    int lrow = idx >> 5, k4 = idx & 31;
    int grow = vb + lrow;
    grow = grow < VV ? grow : VV - 1;
    return ((const float4*)(fcW + (size_t)grow * DD))[cc * 32 + k4];
  };

  {  // prologue
    float4 w0 = wsrc(0, tid), w1 = wsrc(0, 512 + tid);
    float4 a0 = xa4[tid], a1 = xa4[512 + tid];
    float4* wd = (float4*)&wlds[0][0][0];
    float4* ad = (float4*)&alds[0][0];
    wd[tid] = w0; wd[512 + tid] = w1;
    ad[tid] = a0; ad[512 + tid] = a1;
  }
  __syncthreads();

  float c0 = 0.f, c1 = 0.f;
  for (int cc = 0; cc < NC; ++cc) {
    const int cb = cc & 1;
    float4 pw0, pw1, pa0, pa1;
    const bool pref = (cc + 1 < NC);
    if (pref) {
      pw0 = wsrc(cc + 1, tid); pw1 = wsrc(cc + 1, 512 + tid);
      pa0 = xa4[(cc + 1) * 1024 + tid]; pa1 = xa4[(cc + 1) * 1024 + 512 + tid];
    }
#pragma unroll 8
    for (int k4 = 0; k4 < 32; ++k4) {
      float4 a4 = *(const float4*)&alds[cb][(k4 * 32 + b) * 4];
      float4 w0 = *(const float4*)&wlds[cb][r0][k4 * 4];
      float4 w1 = *(const float4*)&wlds[cb][r1][k4 * 4];
      DOT4A(c0, w0, a4);
      DOT4A(c1, w1, a4);
    }
    __syncthreads();
    if (pref) {
      float4* wd = (float4*)&wlds[cb ^ 1][0][0];
      float4* ad = (float4*)&alds[cb ^ 1][0];
      wd[tid] = pw0; wd[512 + tid] = pw1;
      ad[tid] = pa0; ad[512 + tid] = pa1;
    }
    __syncthreads();
  }

  const int v0 = vb + r0, v1 = vb + r1;
  const size_t obase = (size_t)b * SS * VV + (size_t)(t + 1) * VV;
  unsigned long long key0 = 0ull, key1 = 0ull;
  if (v0 < VV) {
    float l0 = c0 + fcb[v0];
    out[obase + v0] = l0;
    key0 = ((unsigned long long)enc_f32(l0) << 32) | (0xFFFFFFFFu - (unsigned)v0);
  }
  if (v1 < VV) {
    float l1 = c1 + fcb[v1];
    out[obase + v1] = l1;
    key1 = ((unsigned long long)enc_f32(l1) << 32) | (0xFFFFFFFFu - (unsigned)v1);
  }
  kred[slot][b] = key0 > key1 ? key0 : key1;
  __syncthreads();
#pragma unroll
  for (int m = 8; m >= 1; m >>= 1) {
    if (slot < m) {
      unsigned long long o = kred[slot + m][b];
      if (o > kred[slot][b]) kred[slot][b] = o;
    }
    __syncthreads();
  }
  if (slot == 0) atomicMax(&winners[(t & 1) * 32 + b], kred[0][b]);
  if (blockIdx.x == 0 && slot == 1) winners[((t + 1) & 1) * 32 + b] = 0ull;
}

extern "C" void kernel_launch(void* const* d_in, const int* in_sizes, int n_in,
                              void* d_out, int out_size, void* d_ws, size_t ws_size,
                              hipStream_t stream) {
  const int*   x         = (const int*)d_in[0];
  const float* emb       = (const float*)d_in[1];
  const float* Wih_f     = (const float*)d_in[2];
  const float* Whh_f     = (const float*)d_in[3];
  const float* b_f       = (const float*)d_in[4];
  const float* Wih_b     = (const float*)d_in[5];
  const float* Whh_b     = (const float*)d_in[6];
  const float* b_b       = (const float*)d_in[7];
  const float* Wih_d     = (const float*)d_in[8];
  const float* Whh_d     = (const float*)d_in[9];
  const float* b_d       = (const float*)d_in[10];
  const float* enc_gamma = (const float*)d_in[11];
  const float* enc_beta  = (const float*)d_in[12];
  const float* dec_gamma = (const float*)d_in[13];
  const float* dec_beta  = (const float*)d_in[14];
  const float* fcW       = (const float*)d_in[15];
  const float* fcb       = (const float*)d_in[16];
  float* out = (float*)d_out;
  float* ws  = (float*)d_ws;

  size_t off = 0;
  float* xeT = ws + off; off += (size_t)SS * EE * BB;
  float* hfT = ws + off; off += 2 * HH * BB;   // start of contiguous zero block
  float* hbT = ws + off; off += 2 * HH * BB;
  float* cfT = ws + off; off += HH * BB;
  float* cbT = ws + off; off += HH * BB;
  float* hdT = ws + off; off += 2 * DD * BB;
  float* cdT = ws + off; off += DD * BB;
  float* outT = ws + off; off += DD * BB;
  unsigned long long* winners = (unsigned long long*)(ws + off); off += 128;

  const int nz = 2 * HH * BB * 2 + HH * BB * 2 + 2 * DD * BB + DD * BB;
  k_zero<<<(nz + 255) / 256, 256, 0, stream>>>(hfT, nz);
  k_out0<<<(BB * VV + 255) / 256, 256, 0, stream>>>(out, winners);
  k_embed<<<(SS * EE * BB) / 256, 256, 0, stream>>>(x, emb, xeT);

  for (int t = 0; t < SS; ++t)
    k_enc_step<<<256, 512, 0, stream>>>(t, xeT, hfT, cfT, hbT, cbT,
                                        Wih_f, Whh_f, b_f, Wih_b, Whh_b, b_b);

  k_enc_bn<<<DD / 8, 256, 0, stream>>>(hfT, hbT, enc_gamma, enc_beta, hdT);

  for (int t = 0; t < SS - 1; ++t) {
    k_dec_gates<<<DD / 8, 512, 0, stream>>>(t, x, emb, hdT, cdT, outT,
                                            Wih_d, Whh_d, b_d,
                                            dec_gamma, dec_beta, winners);
    k_fc<<<(VV + 31) / 32, 512, 0, stream>>>(t, outT, fcW, fcb, out, winners);
  }
}

// Round 7
// 20891.260 us; speedup vs baseline: 6.4887x; 1.7806x over previous
//
#include <hip/hip_runtime.h>
#include <math.h>

#define BB 32
#define SS 256
#define EE 512
#define HH 1024
#define DD 2048
#define VV 10000

// ---------------------------------------------------------------------------
// Activation layout: f4-grid [K/4][32], where column col(b) = (b&3)*8 + (b>>2).
// float4 at [k4][col] = 4 consecutive K-values of batch b.
// Thread mapping in GEMM kernels: tid = rg(0..7) | bg(0..7)<<3 | s(0..7)<<6.
//   wave <-> s (K-slice). Thread computes rows {rg+8i} x batches {4bg+j}.
//   a-read f4 idx = k4*32 + j*8 + bg  -> bank group = bg  (rg broadcasts) OK
//   w-read f4 idx = (rg+8i)*33 + k4   -> bank group = (rg+k4)%8 (bg bcast) OK
//   (w rows padded to 33 f4.)  K-split by stride: k4 = 8*sub + s.
// Per k4: 8-9 LDS f4 reads for 64-80 FMA (2 B/FMA) -> VALU-bound.
// ---------------------------------------------------------------------------

#define DOT4A(acc, q, r)                                                      \
  acc = fmaf((q).x, (r).x, acc); acc = fmaf((q).y, (r).y, acc);               \
  acc = fmaf((q).z, (r).z, acc); acc = fmaf((q).w, (r).w, acc);

__device__ __forceinline__ unsigned enc_f32(float f) {
  unsigned u = __float_as_uint(f);
  return (u & 0x80000000u) ? ~u : (u | 0x80000000u);
}
__device__ __forceinline__ float sigm(float v) {
  return 1.0f / (1.0f + expf(-v));
}
__device__ __forceinline__ int colof(int b) { return (b & 3) * 8 + (b >> 2); }

__global__ __launch_bounds__(256) void k_zero(float* __restrict__ p, int n) {
  int i = blockIdx.x * 256 + threadIdx.x;
  if (i < n) p[i] = 0.0f;
}

__global__ __launch_bounds__(256) void k_out0(float* __restrict__ out,
                                              unsigned long long* __restrict__ winners) {
  int i = blockIdx.x * 256 + threadIdx.x;
  if (i < BB * VV) {
    int b = i / VV, v = i % VV;
    out[(size_t)b * SS * VV + v] = 0.0f;
  }
  if (i < 64) winners[i] = 0ull;
}

// xeT[s][k4][col][c] = emb[x[b][s]][4*k4+c], b = (col&7)*4 + (col>>3)
__global__ __launch_bounds__(256) void k_embed(const int* __restrict__ x,
                                               const float* __restrict__ emb,
                                               float* __restrict__ xeT) {
  int i = blockIdx.x * 256 + threadIdx.x;
  int c = i & 3;
  int col = (i >> 2) & 31;
  int k4 = (i >> 7) & 127;
  int s = i >> 14;
  int b = (col & 7) * 4 + (col >> 3);
  xeT[i] = emb[(size_t)x[b * SS + s] * EE + (k4 * 4 + c)];
}

// ---------------- encoder step (both dirs), fused LSTM cell -----------------
// grid 256: blk>>7 = dir, cells jb..jb+7. 512 thr. Rows: gate i, cell rg.
__global__ __launch_bounds__(512, 2) void k_enc_step(
    int t, const float* __restrict__ xeT,
    float* __restrict__ hfT, float* __restrict__ cfT,
    float* __restrict__ hbT, float* __restrict__ cbT,
    const float* __restrict__ Wih_f, const float* __restrict__ Whh_f,
    const float* __restrict__ b_f,
    const float* __restrict__ Wih_b, const float* __restrict__ Whh_b,
    const float* __restrict__ b_b) {
  __shared__ float wlds[2][32 * 33 * 4];  // 33.8 KB (rows padded to 33 f4)
  __shared__ float alds[2][1024 * 4];     // 32 KB

  const int tid = threadIdx.x;
  const int rg = tid & 7, bg = (tid >> 3) & 7, s = tid >> 6;
  const int dir = blockIdx.x >> 7;
  const int jb = (blockIdx.x & 127) * 8;
  const float* __restrict__ Wih = dir ? Wih_b : Wih_f;
  const float* __restrict__ Whh = dir ? Whh_b : Whh_f;
  const float* __restrict__ bias = dir ? b_b : b_f;
  float* hT = dir ? hbT : hfT;
  float* cT = dir ? cbT : cfT;
  const int sstep = dir ? (SS - 1 - t) : t;
  const int pin = t & 1;
  const float4* __restrict__ hin4 = (const float4*)(hT + pin * (HH * BB));
  const float4* __restrict__ xs4 = (const float4*)(xeT + (size_t)sstep * EE * BB);
  float* __restrict__ hout = hT + (pin ^ 1) * (HH * BB);

  const int NC = 12;  // 8 h-chunks (K=1024) + 4 x-chunks (K=512)

  auto wsrc = [&](int cc, int idx) -> float4 {
    int lrow = idx >> 5, k4 = idx & 31;
    int grow = (lrow >> 3) * HH + jb + (lrow & 7);
    return (cc < 8)
               ? ((const float4*)(Whh + (size_t)grow * HH))[cc * 32 + k4]
               : ((const float4*)(Wih + (size_t)grow * EE))[(cc - 8) * 32 + k4];
  };
  auto asrc = [&](int cc, int idx) -> float4 {
    return (cc < 8) ? hin4[cc * 1024 + idx] : xs4[(cc - 8) * 1024 + idx];
  };
  auto wdst = [&](int buf, int idx) -> float4* {
    return (float4*)&wlds[buf][((idx >> 5) * 33 + (idx & 31)) * 4];
  };

  {  // prologue: stage chunk 0
    float4 w0 = wsrc(0, tid), w1 = wsrc(0, 512 + tid);
    float4 a0 = asrc(0, tid), a1 = asrc(0, 512 + tid);
    *wdst(0, tid) = w0; *wdst(0, 512 + tid) = w1;
    ((float4*)alds[0])[tid] = a0; ((float4*)alds[0])[512 + tid] = a1;
  }
  __syncthreads();

  float acc[4][4];
#pragma unroll
  for (int i = 0; i < 4; ++i)
#pragma unroll
    for (int j = 0; j < 4; ++j) acc[i][j] = 0.0f;

  for (int cc = 0; cc < NC; ++cc) {
    const int cb = cc & 1;
    float4 pw0, pw1, pa0, pa1;
    const bool pref = (cc + 1 < NC);
    if (pref) {  // issue next-chunk loads early
      pw0 = wsrc(cc + 1, tid); pw1 = wsrc(cc + 1, 512 + tid);
      pa0 = asrc(cc + 1, tid); pa1 = asrc(cc + 1, 512 + tid);
    }
    const float4* __restrict__ ap = (const float4*)alds[cb];
    const float4* __restrict__ wp = (const float4*)wlds[cb];
#pragma unroll
    for (int sub = 0; sub < 4; ++sub) {
      const int k4 = sub * 8 + s;
      float4 av[4], wv[4];
#pragma unroll
      for (int j = 0; j < 4; ++j) av[j] = ap[k4 * 32 + j * 8 + bg];
#pragma unroll
      for (int i = 0; i < 4; ++i) wv[i] = wp[(rg + 8 * i) * 33 + k4];
#pragma unroll
      for (int i = 0; i < 4; ++i)
#pragma unroll
        for (int j = 0; j < 4; ++j) { DOT4A(acc[i][j], wv[i], av[j]); }
    }
    if (pref) {
      *wdst(cb ^ 1, tid) = pw0; *wdst(cb ^ 1, 512 + tid) = pw1;
      ((float4*)alds[cb ^ 1])[tid] = pa0; ((float4*)alds[cb ^ 1])[512 + tid] = pa1;
    }
    __syncthreads();
  }

  // 8-way slice reduce via LDS (alias wlds: needs 32KB <= 33.8KB)
  float* red = &wlds[0][0];
#pragma unroll
  for (int i = 0; i < 4; ++i)
#pragma unroll
    for (int j = 0; j < 4; ++j)
      red[(s * 32 + (rg + 8 * i)) * 32 + (bg * 4 + j)] = acc[i][j];
  __syncthreads();

  if (tid < 256) {
    const int c = tid >> 5, b = tid & 31;
    float g4[4];
#pragma unroll
    for (int g = 0; g < 4; ++g) {
      float v = bias[g * HH + jb + c];
#pragma unroll
      for (int s2 = 0; s2 < 8; ++s2) v += red[(s2 * 32 + g * 8 + c) * 32 + b];
      g4[g] = v;
    }
    const int j = jb + c;
    const int idx = j * BB + b;
    float cv = fmaf(sigm(g4[1]), cT[idx], sigm(g4[0]) * tanhf(g4[2]));
    cT[idx] = cv;
    hout[(j >> 2) * 128 + colof(b) * 4 + (j & 3)] = sigm(g4[3]) * tanhf(cv);
  }
}

// hn = relu(bn(concat(hf, hb))) -> hdT parity 0
__global__ __launch_bounds__(256) void k_enc_bn(
    const float* __restrict__ hfT, const float* __restrict__ hbT,
    const float* __restrict__ gamma, const float* __restrict__ beta,
    float* __restrict__ hdT) {
  const int d = blockIdx.x * 8 + (threadIdx.x >> 5);
  const int b = threadIdx.x & 31;
  const int dl = (d < HH) ? d : d - HH;
  const float* __restrict__ src = (d < HH) ? hfT : hbT;
  float v = src[(dl >> 2) * 128 + colof(b) * 4 + (dl & 3)];
  float sum = v;
  for (int m = 16; m >= 1; m >>= 1) sum += __shfl_xor(sum, m, 32);
  float mean = sum * (1.0f / BB);
  float dx = v - mean;
  float s2 = dx * dx;
  for (int m = 16; m >= 1; m >>= 1) s2 += __shfl_xor(s2, m, 32);
  float var = s2 * (1.0f / BB);
  float y = dx * (1.0f / sqrtf(var + 1e-5f)) * gamma[d] + beta[d];
  hdT[(d >> 2) * 128 + colof(b) * 4 + (d & 3)] = fmaxf(y, 0.0f);
}

// ---------------- decoder gates + fused cell + BN + emb gather --------------
// grid 256 blocks: cells jb..jb+7.
__global__ __launch_bounds__(512, 2) void k_dec_gates(
    int t, const int* __restrict__ x, const float* __restrict__ emb,
    float* __restrict__ hdT, float* __restrict__ cdT, float* __restrict__ outT,
    const float* __restrict__ Wih, const float* __restrict__ Whh,
    const float* __restrict__ bias,
    const float* __restrict__ gamma, const float* __restrict__ beta,
    const unsigned long long* __restrict__ winners) {
  __shared__ float wlds[2][32 * 33 * 4];
  __shared__ float alds[2][1024 * 4];
  __shared__ int stoks[32];

  const int tid = threadIdx.x;
  const int rg = tid & 7, bg = (tid >> 3) & 7, s = tid >> 6;
  const int jb = blockIdx.x * 8;
  const int pin = t & 1;
  const float4* __restrict__ hin4 = (const float4*)(hdT + pin * (DD * BB));
  float* __restrict__ hout = hdT + (pin ^ 1) * (DD * BB);

  if (tid < 32)
    stoks[tid] = (t == 0)
                     ? x[tid * SS]
                     : (int)(0xFFFFFFFFu -
                             (unsigned)(winners[((t - 1) & 1) * 32 + tid] &
                                        0xFFFFFFFFull));

  const int NC = 20;  // 16 h-chunks (K=2048) + 4 emb-chunks (K=512)

  auto wsrc = [&](int cc, int idx) -> float4 {
    int lrow = idx >> 5, k4 = idx & 31;
    int grow = (lrow >> 3) * DD + jb + (lrow & 7);
    return (cc < 16)
               ? ((const float4*)(Whh + (size_t)grow * DD))[cc * 32 + k4]
               : ((const float4*)(Wih + (size_t)grow * EE))[(cc - 16) * 32 + k4];
  };
  auto asrc = [&](int cc, int idx) -> float4 {
    if (cc < 16) return hin4[cc * 1024 + idx];
    int col = idx & 31;
    int b = (col & 7) * 4 + (col >> 3);
    return ((const float4*)(emb + (size_t)stoks[b] * EE))[(cc - 16) * 32 +
                                                          (idx >> 5)];
  };
  auto wdst = [&](int buf, int idx) -> float4* {
    return (float4*)&wlds[buf][((idx >> 5) * 33 + (idx & 31)) * 4];
  };

  {  // prologue: chunk 0 is h-part (stoks not needed yet)
    float4 w0 = wsrc(0, tid), w1 = wsrc(0, 512 + tid);
    float4 a0 = asrc(0, tid), a1 = asrc(0, 512 + tid);
    *wdst(0, tid) = w0; *wdst(0, 512 + tid) = w1;
    ((float4*)alds[0])[tid] = a0; ((float4*)alds[0])[512 + tid] = a1;
  }
  __syncthreads();

  float acc[4][4];
#pragma unroll
  for (int i = 0; i < 4; ++i)
#pragma unroll
    for (int j = 0; j < 4; ++j) acc[i][j] = 0.0f;

  for (int cc = 0; cc < NC; ++cc) {
    const int cb = cc & 1;
    float4 pw0, pw1, pa0, pa1;
    const bool pref = (cc + 1 < NC);
    if (pref) {
      pw0 = wsrc(cc + 1, tid); pw1 = wsrc(cc + 1, 512 + tid);
      pa0 = asrc(cc + 1, tid); pa1 = asrc(cc + 1, 512 + tid);
    }
    const float4* __restrict__ ap = (const float4*)alds[cb];
    const float4* __restrict__ wp = (const float4*)wlds[cb];
#pragma unroll
    for (int sub = 0; sub < 4; ++sub) {
      const int k4 = sub * 8 + s;
      float4 av[4], wv[4];
#pragma unroll
      for (int j = 0; j < 4; ++j) av[j] = ap[k4 * 32 + j * 8 + bg];
#pragma unroll
      for (int i = 0; i < 4; ++i) wv[i] = wp[(rg + 8 * i) * 33 + k4];
#pragma unroll
      for (int i = 0; i < 4; ++i)
#pragma unroll
        for (int j = 0; j < 4; ++j) { DOT4A(acc[i][j], wv[i], av[j]); }
    }
    if (pref) {
      *wdst(cb ^ 1, tid) = pw0; *wdst(cb ^ 1, 512 + tid) = pw1;
      ((float4*)alds[cb ^ 1])[tid] = pa0; ((float4*)alds[cb ^ 1])[512 + tid] = pa1;
    }
    __syncthreads();
  }

  float* red = &wlds[0][0];
#pragma unroll
  for (int i = 0; i < 4; ++i)
#pragma unroll
    for (int j = 0; j < 4; ++j)
      red[(s * 32 + (rg + 8 * i)) * 32 + (bg * 4 + j)] = acc[i][j];
  __syncthreads();

  if (tid < 256) {
    const int c = tid >> 5, b = tid & 31;
    float g4[4];
#pragma unroll
    for (int g = 0; g < 4; ++g) {
      float v = bias[g * DD + jb + c];
#pragma unroll
      for (int s2 = 0; s2 < 8; ++s2) v += red[(s2 * 32 + g * 8 + c) * 32 + b];
      g4[g] = v;
    }
    const int j = jb + c;
    const int idx = j * BB + b;
    float cv = fmaf(sigm(g4[1]), cdT[idx], sigm(g4[0]) * tanhf(g4[2]));
    cdT[idx] = cv;
    float h = sigm(g4[3]) * tanhf(cv);
    hout[(j >> 2) * 128 + colof(b) * 4 + (j & 3)] = h;
    // fused BN over batch + relu
    float sum = h;
    for (int m = 16; m >= 1; m >>= 1) sum += __shfl_xor(sum, m, 32);
    float mean = sum * (1.0f / BB);
    float dx = h - mean;
    float s2v = dx * dx;
    for (int m = 16; m >= 1; m >>= 1) s2v += __shfl_xor(s2v, m, 32);
    float var = s2v * (1.0f / BB);
    float y = dx * (1.0f / sqrtf(var + 1e-5f)) * gamma[j] + beta[j];
    outT[(j >> 2) * 128 + colof(b) * 4 + (j & 3)] = fmaxf(y, 0.0f);
  }
}

// ---------------- fc + fused argmax ------------------------------------------
// grid 250 blocks x 40 rows (exact). Thread tile 5 rows x 4 b.
__global__ __launch_bounds__(512, 2) void k_fc(
    int t, const float* __restrict__ outT, const float* __restrict__ fcW,
    const float* __restrict__ fcb, float* __restrict__ out,
    unsigned long long* __restrict__ winners) {
  __shared__ float wlds[2][40 * 33 * 4];  // 42.2 KB
  __shared__ float alds[2][1024 * 4];
  __shared__ unsigned long long kred[16][32];

  const int tid = threadIdx.x;
  const int rg = tid & 7, bg = (tid >> 3) & 7, s = tid >> 6;
  const int vb = blockIdx.x * 40;
  const float4* __restrict__ xa4 = (const float4*)outT;

  const int NC = 16;  // K = 2048

  auto wsrc = [&](int cc, int idx) -> float4 {
    int lrow = idx >> 5, k4 = idx & 31;
    return ((const float4*)(fcW + (size_t)(vb + lrow) * DD))[cc * 32 + k4];
  };
  auto wdst = [&](int buf, int idx) -> float4* {
    return (float4*)&wlds[buf][((idx >> 5) * 33 + (idx & 31)) * 4];
  };

  {  // prologue (W chunk = 1280 f4: 2.5 per thread)
    float4 w0 = wsrc(0, tid), w1 = wsrc(0, 512 + tid);
    float4 a0 = xa4[tid], a1 = xa4[512 + tid];
    *wdst(0, tid) = w0; *wdst(0, 512 + tid) = w1;
    if (tid < 256) *wdst(0, 1024 + tid) = wsrc(0, 1024 + tid);
    ((float4*)alds[0])[tid] = a0; ((float4*)alds[0])[512 + tid] = a1;
  }
  __syncthreads();

  float acc[5][4];
#pragma unroll
  for (int i = 0; i < 5; ++i)
#pragma unroll
    for (int j = 0; j < 4; ++j) acc[i][j] = 0.0f;

  for (int cc = 0; cc < NC; ++cc) {
    const int cb = cc & 1;
    float4 pw0, pw1, pw2, pa0, pa1;
    const bool pref = (cc + 1 < NC);
    if (pref) {
      pw0 = wsrc(cc + 1, tid); pw1 = wsrc(cc + 1, 512 + tid);
      if (tid < 256) pw2 = wsrc(cc + 1, 1024 + tid);
      pa0 = xa4[(cc + 1) * 1024 + tid];
      pa1 = xa4[(cc + 1) * 1024 + 512 + tid];
    }
    const float4* __restrict__ ap = (const float4*)alds[cb];
    const float4* __restrict__ wp = (const float4*)wlds[cb];
#pragma unroll
    for (int sub = 0; sub < 4; ++sub) {
      const int k4 = sub * 8 + s;
      float4 av[4], wv[5];
#pragma unroll
      for (int j = 0; j < 4; ++j) av[j] = ap[k4 * 32 + j * 8 + bg];
#pragma unroll
      for (int i = 0; i < 5; ++i) wv[i] = wp[(rg + 8 * i) * 33 + k4];
#pragma unroll
      for (int i = 0; i < 5; ++i)
#pragma unroll
        for (int j = 0; j < 4; ++j) { DOT4A(acc[i][j], wv[i], av[j]); }
    }
    if (pref) {
      *wdst(cb ^ 1, tid) = pw0; *wdst(cb ^ 1, 512 + tid) = pw1;
      if (tid < 256) *wdst(cb ^ 1, 1024 + tid) = pw2;
      ((float4*)alds[cb ^ 1])[tid] = pa0; ((float4*)alds[cb ^ 1])[512 + tid] = pa1;
    }
    __syncthreads();
  }

  // slice reduce (alias wlds: 8*40*32*4B = 40.96KB <= 42.2KB)
  float* red = &wlds[0][0];
#pragma unroll
  for (int i = 0; i < 5; ++i)
#pragma unroll
    for (int j = 0; j < 4; ++j)
      red[(s * 40 + (rg + 8 * i)) * 32 + (bg * 4 + j)] = acc[i][j];
  __syncthreads();

  const int r = tid >> 5, b = tid & 31;  // r 0..15
  const size_t obase = (size_t)b * SS * VV + (size_t)(t + 1) * VV;
  unsigned long long bestkey = 0ull;
  for (int lrow = r; lrow < 40; lrow += 16) {
    const int v = vb + lrow;
    float val = fcb[v];
#pragma unroll
    for (int s2 = 0; s2 < 8; ++s2) val += red[(s2 * 40 + lrow) * 32 + b];
    out[obase + v] = val;
    unsigned long long key =
        ((unsigned long long)enc_f32(val) << 32) | (0xFFFFFFFFu - (unsigned)v);
    if (key > bestkey) bestkey = key;
  }
  kred[r][b] = bestkey;
  __syncthreads();
#pragma unroll
  for (int m = 8; m >= 1; m >>= 1) {
    if (r < m) {
      unsigned long long o = kred[r + m][b];
      if (o > kred[r][b]) kred[r][b] = o;
    }
    __syncthreads();
  }
  if (r == 0) atomicMax(&winners[(t & 1) * 32 + b], kred[0][b]);
  if (blockIdx.x == 0 && r == 1) winners[((t + 1) & 1) * 32 + b] = 0ull;
}

extern "C" void kernel_launch(void* const* d_in, const int* in_sizes, int n_in,
                              void* d_out, int out_size, void* d_ws, size_t ws_size,
                              hipStream_t stream) {
  const int*   x         = (const int*)d_in[0];
  const float* emb       = (const float*)d_in[1];
  const float* Wih_f     = (const float*)d_in[2];
  const float* Whh_f     = (const float*)d_in[3];
  const float* b_f       = (const float*)d_in[4];
  const float* Wih_b     = (const float*)d_in[5];
  const float* Whh_b     = (const float*)d_in[6];
  const float* b_b       = (const float*)d_in[7];
  const float* Wih_d     = (const float*)d_in[8];
  const float* Whh_d     = (const float*)d_in[9];
  const float* b_d       = (const float*)d_in[10];
  const float* enc_gamma = (const float*)d_in[11];
  const float* enc_beta  = (const float*)d_in[12];
  const float* dec_gamma = (const float*)d_in[13];
  const float* dec_beta  = (const float*)d_in[14];
  const float* fcW       = (const float*)d_in[15];
  const float* fcb       = (const float*)d_in[16];
  float* out = (float*)d_out;
  float* ws  = (float*)d_ws;

  size_t off = 0;
  float* xeT = ws + off; off += (size_t)SS * EE * BB;
  float* hfT = ws + off; off += 2 * HH * BB;   // start of contiguous zero block
  float* hbT = ws + off; off += 2 * HH * BB;
  float* cfT = ws + off; off += HH * BB;
  float* cbT = ws + off; off += HH * BB;
  float* hdT = ws + off; off += 2 * DD * BB;
  float* cdT = ws + off; off += DD * BB;
  float* outT = ws + off; off += DD * BB;
  unsigned long long* winners = (unsigned long long*)(ws + off); off += 128;

  const int nz = 2 * HH * BB * 2 + HH * BB * 2 + 2 * DD * BB + DD * BB;
  k_zero<<<(nz + 255) / 256, 256, 0, stream>>>(hfT, nz);
  k_out0<<<(BB * VV + 255) / 256, 256, 0, stream>>>(out, winners);
  k_embed<<<(SS * EE * BB) / 256, 256, 0, stream>>>(x, emb, xeT);

  for (int t = 0; t < SS; ++t)
    k_enc_step<<<256, 512, 0, stream>>>(t, xeT, hfT, cfT, hbT, cbT,
                                        Wih_f, Whh_f, b_f, Wih_b, Whh_b, b_b);

  k_enc_bn<<<DD / 8, 256, 0, stream>>>(hfT, hbT, enc_gamma, enc_beta, hdT);

  for (int t = 0; t < SS - 1; ++t) {
    k_dec_gates<<<DD / 8, 512, 0, stream>>>(t, x, emb, hdT, cdT, outT,
                                            Wih_d, Whh_d, b_d,
                                            dec_gamma, dec_beta, winners);
    k_fc<<<VV / 40, 512, 0, stream>>>(t, outT, fcW, fcb, out, winners);
  }
}

// Round 8
// 12636.872 us; speedup vs baseline: 10.7271x; 1.6532x over previous
//
#include <hip/hip_runtime.h>
#include <math.h>

#define BB 32
#define SS 256
#define EE 512
#define HH 1024
#define DD 2048
#define VV 10000

typedef __attribute__((ext_vector_type(8))) short short8v;   // 8 bf16 frag
typedef __attribute__((ext_vector_type(4))) float f32x4;     // C/D frag

typedef unsigned short ushort_t;
typedef unsigned long long u64;

// ---------------------------------------------------------------------------
// MFMA path: C[b][n] via mfma_f32_16x16x32_bf16, M=batch(2 tiles), N=rows.
// fp32 emulated as hi+lo bf16 (3 products, lo*lo dropped: ~2^-16 rel err).
// All operands pre-packed as [fpkt][plane][ntile][lane][8bf16] fragments ->
// frag load = one coalesced global_load_dwordx4, NO LDS in main loop.
// Row order for gates/enc is permuted so a block owns 4 gates x 8 cells
// (round-7 epilogue carried verbatim). k-slice reduce via LDS at the end.
// ---------------------------------------------------------------------------

__device__ __forceinline__ ushort_t f2bf(float f) {  // RTN-even fp32->bf16
  unsigned u = __float_as_uint(f);
  return (ushort_t)((u + 0x7FFFu + ((u >> 16) & 1u)) >> 16);
}
__device__ __forceinline__ float bf2f(ushort_t h) {
  return __uint_as_float(((unsigned)h) << 16);
}
__device__ __forceinline__ unsigned enc_f32(float f) {
  unsigned u = __float_as_uint(f);
  return (u & 0x80000000u) ? ~u : (u | 0x80000000u);
}
__device__ __forceinline__ float sigm(float v) { return 1.0f / (1.0f + expf(-v)); }

union Frag { short8v v; ushort_t u[8]; };

// ---------------- one-time packing kernels ---------------------------------
// W'[fpkt][plane2][ntile][lane64][8]; value = W[n(rho)][k], rho=ntile*16+(l&15),
// k = fpkt*32 + (l>>4)*8 + e.
__global__ __launch_bounds__(256) void k_pack_wdec(const float* __restrict__ Whh,
                                                   const float* __restrict__ Wih,
                                                   ushort_t* __restrict__ Wp) {
  int i = blockIdx.x * 256 + threadIdx.x;       // (fpkt 80, nt 512, lane 64)
  int lane = i & 63, nt = (i >> 6) & 511, fpkt = i >> 15;
  int rho = nt * 16 + (lane & 15);
  int blk = rho >> 5, idx = rho & 31, g = idx >> 3, c = idx & 7;
  int n = g * DD + blk * 8 + c;
  int k0 = fpkt * 32 + (lane >> 4) * 8;
  const float* src = (k0 < DD) ? (Whh + (size_t)n * DD + k0)
                               : (Wih + (size_t)n * EE + (k0 - DD));
  size_t ohi = ((((size_t)fpkt * 2 + 0) * 512 + nt) * 64 + lane) * 8;
  size_t olo = ((((size_t)fpkt * 2 + 1) * 512 + nt) * 64 + lane) * 8;
#pragma unroll
  for (int e = 0; e < 8; ++e) {
    float v = src[e];
    ushort_t hi = f2bf(v);
    Wp[ohi + e] = hi;
    Wp[olo + e] = f2bf(v - bf2f(hi));
  }
}

__global__ __launch_bounds__(256) void k_pack_wfc(const float* __restrict__ fcW,
                                                  ushort_t* __restrict__ Wp) {
  int i = blockIdx.x * 256 + threadIdx.x;       // (fpkt 64, nt 626, lane 64)
  int lane = i & 63, nt = (i >> 6) % 626, fpkt = i / (626 * 64);
  int rho = nt * 16 + (lane & 15);
  int n = rho < VV ? rho : VV - 1;
  int k0 = fpkt * 32 + (lane >> 4) * 8;
  const float* src = fcW + (size_t)n * DD + k0;
  size_t ohi = ((((size_t)fpkt * 2 + 0) * 626 + nt) * 64 + lane) * 8;
  size_t olo = ((((size_t)fpkt * 2 + 1) * 626 + nt) * 64 + lane) * 8;
#pragma unroll
  for (int e = 0; e < 8; ++e) {
    float v = src[e];
    ushort_t hi = f2bf(v);
    Wp[ohi + e] = hi;
    Wp[olo + e] = f2bf(v - bf2f(hi));
  }
}

__global__ __launch_bounds__(256) void k_pack_wenc(
    const float* __restrict__ Whh_f, const float* __restrict__ Wih_f,
    const float* __restrict__ Whh_b, const float* __restrict__ Wih_b,
    ushort_t* __restrict__ Wp) {
  int i = blockIdx.x * 256 + threadIdx.x;       // (fpkt 48, nt 512, lane 64)
  int lane = i & 63, nt = (i >> 6) & 511, fpkt = i >> 15;
  int rho = nt * 16 + (lane & 15);
  int blk = rho >> 5, idx = rho & 31, g = idx >> 3, c = idx & 7;
  int dir = blk >> 7;
  int r = g * HH + (blk & 127) * 8 + c;
  const float* Whh = dir ? Whh_b : Whh_f;
  const float* Wih = dir ? Wih_b : Wih_f;
  int k0 = fpkt * 32 + (lane >> 4) * 8;
  const float* src = (k0 < HH) ? (Whh + (size_t)r * HH + k0)
                               : (Wih + (size_t)r * EE + (k0 - HH));
  size_t ohi = ((((size_t)fpkt * 2 + 0) * 512 + nt) * 64 + lane) * 8;
  size_t olo = ((((size_t)fpkt * 2 + 1) * 512 + nt) * 64 + lane) * 8;
#pragma unroll
  for (int e = 0; e < 8; ++e) {
    float v = src[e];
    ushort_t hi = f2bf(v);
    Wp[ohi + e] = hi;
    Wp[olo + e] = f2bf(v - bf2f(hi));
  }
}

__global__ __launch_bounds__(256) void k_zero32(unsigned* __restrict__ p, int n) {
  int i = blockIdx.x * 256 + threadIdx.x;
  if (i < n) p[i] = 0u;
}
__global__ __launch_bounds__(256) void k_out0(float* __restrict__ out) {
  int i = blockIdx.x * 256 + threadIdx.x;
  if (i < BB * VV) out[(size_t)(i / VV) * SS * VV + (i % VV)] = 0.0f;
}

// helper: write one fp32 value as hi/lo planes into an act-frag array
// layout [fpkt][plane][mtile][lane64][8], k = index j, batch b.
__device__ __forceinline__ void pack_act(ushort_t* __restrict__ dst, int j, int b,
                                         float v) {
  int fpkt = j >> 5, kloc = j & 31;
  int lane = (kloc >> 3) * 16 + (b & 15);
  int e = kloc & 7, mt = b >> 4;
  ushort_t hi = f2bf(v);
  dst[((((size_t)fpkt * 2 + 0) * 2 + mt) * 64 + lane) * 8 + e] = hi;
  dst[((((size_t)fpkt * 2 + 1) * 2 + mt) * 64 + lane) * 8 + e] = f2bf(v - bf2f(hi));
}

// build hi/lo frags from 8 fp32 (in-register split for embedding k-range)
__device__ __forceinline__ void split8(const float* __restrict__ src, Frag& fh,
                                       Frag& fl) {
  float4 v0 = *(const float4*)src;
  float4 v1 = *(const float4*)(src + 4);
  float vv[8] = {v0.x, v0.y, v0.z, v0.w, v1.x, v1.y, v1.z, v1.w};
#pragma unroll
  for (int e = 0; e < 8; ++e) {
    ushort_t hi = f2bf(vv[e]);
    fh.u[e] = hi;
    fl.u[e] = f2bf(vv[e] - bf2f(hi));
  }
}

// ---------------- encoder step (both dirs), MFMA -----------------------------
// grid 256: dir = blk>>7, cells jb..jb+7 (32 rows = 4 gates x 8 cells).
__global__ __launch_bounds__(512) void k_enc_mfma(
    int t, const int* __restrict__ x, const float* __restrict__ emb,
    const ushort_t* __restrict__ Wp, ushort_t* __restrict__ hencp,
    float* __restrict__ cT2, float* __restrict__ hT2,
    const float* __restrict__ b_f, const float* __restrict__ b_b) {
  __shared__ float red[8 * 2 * 2 * 64 * 4];
  __shared__ int stoks[32];
  const int tid = threadIdx.x, w = tid >> 6, lane = tid & 63;
  const int dir = blockIdx.x >> 7, jb = (blockIdx.x & 127) * 8;
  const int s = dir ? (SS - 1 - t) : t;
  const int pin = t & 1;
  const size_t HEP = 32 * 2 * 2 * 64 * 8;  // ushorts per buffer
  const ushort_t* hin = hencp + (dir * 2 + pin) * HEP;
  ushort_t* hout = hencp + (dir * 2 + (pin ^ 1)) * HEP;
  if (tid < 32) stoks[tid] = x[tid * SS + s];
  __syncthreads();

  f32x4 acc[2][2];
#pragma unroll
  for (int a = 0; a < 2; ++a)
#pragma unroll
    for (int bq = 0; bq < 2; ++bq) acc[a][bq] = (f32x4){0.f, 0.f, 0.f, 0.f};

  for (int i = 0; i < 6; ++i) {
    const int kt = w + 8 * i;
    Frag ah[2], al[2], wh[2], wl[2];
    if (kt < 32) {
#pragma unroll
      for (int mt = 0; mt < 2; ++mt) {
        ah[mt].v = *(const short8v*)(hin + ((((size_t)kt * 2 + 0) * 2 + mt) * 64 + lane) * 8);
        al[mt].v = *(const short8v*)(hin + ((((size_t)kt * 2 + 1) * 2 + mt) * 64 + lane) * 8);
      }
    } else {
      const int ke = (kt - 32) * 32 + (lane >> 4) * 8;
#pragma unroll
      for (int mt = 0; mt < 2; ++mt) {
        const int b = mt * 16 + (lane & 15);
        split8(emb + (size_t)stoks[b] * EE + ke, ah[mt], al[mt]);
      }
    }
#pragma unroll
    for (int nt = 0; nt < 2; ++nt) {
      const size_t ntg = blockIdx.x * 2 + nt;
      wh[nt].v = *(const short8v*)(Wp + ((((size_t)kt * 2 + 0) * 512 + ntg) * 64 + lane) * 8);
      wl[nt].v = *(const short8v*)(Wp + ((((size_t)kt * 2 + 1) * 512 + ntg) * 64 + lane) * 8);
    }
#pragma unroll
    for (int mt = 0; mt < 2; ++mt)
#pragma unroll
      for (int nt = 0; nt < 2; ++nt) {
        acc[mt][nt] = __builtin_amdgcn_mfma_f32_16x16x32_bf16(ah[mt].v, wh[nt].v, acc[mt][nt], 0, 0, 0);
        acc[mt][nt] = __builtin_amdgcn_mfma_f32_16x16x32_bf16(ah[mt].v, wl[nt].v, acc[mt][nt], 0, 0, 0);
        acc[mt][nt] = __builtin_amdgcn_mfma_f32_16x16x32_bf16(al[mt].v, wh[nt].v, acc[mt][nt], 0, 0, 0);
      }
  }
#pragma unroll
  for (int mt = 0; mt < 2; ++mt)
#pragma unroll
    for (int nt = 0; nt < 2; ++nt)
      ((f32x4*)red)[((w * 2 + mt) * 2 + nt) * 64 + lane] = acc[mt][nt];
  __syncthreads();

  if (tid < 256) {
    const int c = tid >> 5, b = tid & 31;
    const float* bias = dir ? b_b : b_f;
    const int mt = b >> 4, lg = (b & 15) >> 2, reg = b & 3;
    float g4[4];
#pragma unroll
    for (int g = 0; g < 4; ++g) {
      const int rho = g * 8 + c;
      const int nt = rho >> 4, l15 = rho & 15;
      float v = bias[g * HH + jb + c];
#pragma unroll
      for (int w2 = 0; w2 < 8; ++w2)
        v += red[(((w2 * 2 + mt) * 2 + nt) * 64 + lg * 16 + l15) * 4 + reg];
      g4[g] = v;
    }
    const int j = jb + c;
    float* cT = cT2 + dir * (HH * BB);
    float* hT = hT2 + dir * (HH * BB);
    const int idx = j * BB + b;
    float cv = fmaf(sigm(g4[1]), cT[idx], sigm(g4[0]) * tanhf(g4[2]));
    cT[idx] = cv;
    float h = sigm(g4[3]) * tanhf(cv);
    hT[idx] = h;                       // fp32 copy (used by final BN)
    pack_act(hout, j, b, h);           // frag-packed for next step
  }
}

// BN + relu on concat(hf,hb) -> packed hd'[parity 0]
__global__ __launch_bounds__(256) void k_bn_handoff(
    const float* __restrict__ hT2, const float* __restrict__ gamma,
    const float* __restrict__ beta, ushort_t* __restrict__ hdp) {
  const int d = blockIdx.x * 8 + (threadIdx.x >> 5);
  const int b = threadIdx.x & 31;
  float v = hT2[(d < HH ? d * BB : (HH * BB) + (d - HH) * BB) + b];
  float sum = v;
  for (int m = 16; m >= 1; m >>= 1) sum += __shfl_xor(sum, m, 32);
  float mean = sum * (1.0f / BB);
  float dx = v - mean;
  float s2 = dx * dx;
  for (int m = 16; m >= 1; m >>= 1) s2 += __shfl_xor(s2, m, 32);
  float var = s2 * (1.0f / BB);
  float y = fmaxf(dx * (1.0f / sqrtf(var + 1e-5f)) * gamma[d] + beta[d], 0.0f);
  pack_act(hdp, d, b, y);
}

// ---------------- decoder gates, MFMA ----------------------------------------
__global__ __launch_bounds__(512) void k_dec_mfma(
    int t, const int* __restrict__ x, const float* __restrict__ emb,
    const ushort_t* __restrict__ Wp, ushort_t* __restrict__ hdp,
    float* __restrict__ cdT, ushort_t* __restrict__ outp,
    const float* __restrict__ bias, const float* __restrict__ gamma,
    const float* __restrict__ beta, const u64* __restrict__ winners) {
  __shared__ float red[8 * 2 * 2 * 64 * 4];
  __shared__ int stoks[32];
  const int tid = threadIdx.x, w = tid >> 6, lane = tid & 63;
  const int jb = blockIdx.x * 8;
  const int pin = t & 1;
  const size_t HDP = 64 * 2 * 2 * 64 * 8;
  const ushort_t* hin = hdp + pin * HDP;
  ushort_t* hout = hdp + (pin ^ 1) * HDP;
  if (tid < 32)
    stoks[tid] = (t == 0) ? x[tid * SS]
                          : (int)(0xFFFFFFFFu -
                                  (unsigned)(winners[((t - 1) & 1) * 32 + tid] & 0xFFFFFFFFull));
  __syncthreads();

  f32x4 acc[2][2];
#pragma unroll
  for (int a = 0; a < 2; ++a)
#pragma unroll
    for (int bq = 0; bq < 2; ++bq) acc[a][bq] = (f32x4){0.f, 0.f, 0.f, 0.f};

  for (int i = 0; i < 10; ++i) {
    const int kt = w + 8 * i;
    Frag ah[2], al[2], wh[2], wl[2];
    if (kt < 64) {
#pragma unroll
      for (int mt = 0; mt < 2; ++mt) {
        ah[mt].v = *(const short8v*)(hin + ((((size_t)kt * 2 + 0) * 2 + mt) * 64 + lane) * 8);
        al[mt].v = *(const short8v*)(hin + ((((size_t)kt * 2 + 1) * 2 + mt) * 64 + lane) * 8);
      }
    } else {
      const int ke = (kt - 64) * 32 + (lane >> 4) * 8;
#pragma unroll
      for (int mt = 0; mt < 2; ++mt) {
        const int b = mt * 16 + (lane & 15);
        split8(emb + (size_t)stoks[b] * EE + ke, ah[mt], al[mt]);
      }
    }
#pragma unroll
    for (int nt = 0; nt < 2; ++nt) {
      const size_t ntg = blockIdx.x * 2 + nt;
      wh[nt].v = *(const short8v*)(Wp + ((((size_t)kt * 2 + 0) * 512 + ntg) * 64 + lane) * 8);
      wl[nt].v = *(const short8v*)(Wp + ((((size_t)kt * 2 + 1) * 512 + ntg) * 64 + lane) * 8);
    }
#pragma unroll
    for (int mt = 0; mt < 2; ++mt)
#pragma unroll
      for (int nt = 0; nt < 2; ++nt) {
        acc[mt][nt] = __builtin_amdgcn_mfma_f32_16x16x32_bf16(ah[mt].v, wh[nt].v, acc[mt][nt], 0, 0, 0);
        acc[mt][nt] = __builtin_amdgcn_mfma_f32_16x16x32_bf16(ah[mt].v, wl[nt].v, acc[mt][nt], 0, 0, 0);
        acc[mt][nt] = __builtin_amdgcn_mfma_f32_16x16x32_bf16(al[mt].v, wh[nt].v, acc[mt][nt], 0, 0, 0);
      }
  }
#pragma unroll
  for (int mt = 0; mt < 2; ++mt)
#pragma unroll
    for (int nt = 0; nt < 2; ++nt)
      ((f32x4*)red)[((w * 2 + mt) * 2 + nt) * 64 + lane] = acc[mt][nt];
  __syncthreads();

  if (tid < 256) {
    const int c = tid >> 5, b = tid & 31;
    const int mt = b >> 4, lg = (b & 15) >> 2, reg = b & 3;
    float g4[4];
#pragma unroll
    for (int g = 0; g < 4; ++g) {
      const int rho = g * 8 + c;
      const int nt = rho >> 4, l15 = rho & 15;
      float v = bias[g * DD + jb + c];
#pragma unroll
      for (int w2 = 0; w2 < 8; ++w2)
        v += red[(((w2 * 2 + mt) * 2 + nt) * 64 + lg * 16 + l15) * 4 + reg];
      g4[g] = v;
    }
    const int j = jb + c;
    const int idx = j * BB + b;
    float cv = fmaf(sigm(g4[1]), cdT[idx], sigm(g4[0]) * tanhf(g4[2]));
    cdT[idx] = cv;
    float h = sigm(g4[3]) * tanhf(cv);
    pack_act(hout, j, b, h);
    // fused BN over batch + relu -> packed fc input
    float sum = h;
    for (int m = 16; m >= 1; m >>= 1) sum += __shfl_xor(sum, m, 32);
    float mean = sum * (1.0f / BB);
    float dx = h - mean;
    float s2v = dx * dx;
    for (int m = 16; m >= 1; m >>= 1) s2v += __shfl_xor(s2v, m, 32);
    float var = s2v * (1.0f / BB);
    float y = fmaxf(dx * (1.0f / sqrtf(var + 1e-5f)) * gamma[j] + beta[j], 0.0f);
    pack_act(outp, j, b, y);
  }
}

// ---------------- fc + fused argmax, MFMA -------------------------------------
// grid 313 blocks x 32 rows (W' padded to 10016).
__global__ __launch_bounds__(512) void k_fc_mfma(
    int t, const ushort_t* __restrict__ outp, const ushort_t* __restrict__ Wp,
    const float* __restrict__ fcb, float* __restrict__ out,
    u64* __restrict__ winners) {
  __shared__ float red[8 * 2 * 2 * 64 * 4];
  __shared__ u64 kred[16][32];
  const int tid = threadIdx.x, w = tid >> 6, lane = tid & 63;

  f32x4 acc[2][2];
#pragma unroll
  for (int a = 0; a < 2; ++a)
#pragma unroll
    for (int bq = 0; bq < 2; ++bq) acc[a][bq] = (f32x4){0.f, 0.f, 0.f, 0.f};

  for (int i = 0; i < 8; ++i) {
    const int kt = w + 8 * i;
    Frag ah[2], al[2], wh[2], wl[2];
#pragma unroll
    for (int mt = 0; mt < 2; ++mt) {
      ah[mt].v = *(const short8v*)(outp + ((((size_t)kt * 2 + 0) * 2 + mt) * 64 + lane) * 8);
      al[mt].v = *(const short8v*)(outp + ((((size_t)kt * 2 + 1) * 2 + mt) * 64 + lane) * 8);
    }
#pragma unroll
    for (int nt = 0; nt < 2; ++nt) {
      const size_t ntg = blockIdx.x * 2 + nt;
      wh[nt].v = *(const short8v*)(Wp + ((((size_t)kt * 2 + 0) * 626 + ntg) * 64 + lane) * 8);
      wl[nt].v = *(const short8v*)(Wp + ((((size_t)kt * 2 + 1) * 626 + ntg) * 64 + lane) * 8);
    }
#pragma unroll
    for (int mt = 0; mt < 2; ++mt)
#pragma unroll
      for (int nt = 0; nt < 2; ++nt) {
        acc[mt][nt] = __builtin_amdgcn_mfma_f32_16x16x32_bf16(ah[mt].v, wh[nt].v, acc[mt][nt], 0, 0, 0);
        acc[mt][nt] = __builtin_amdgcn_mfma_f32_16x16x32_bf16(ah[mt].v, wl[nt].v, acc[mt][nt], 0, 0, 0);
        acc[mt][nt] = __builtin_amdgcn_mfma_f32_16x16x32_bf16(al[mt].v, wh[nt].v, acc[mt][nt], 0, 0, 0);
      }
  }
#pragma unroll
  for (int mt = 0; mt < 2; ++mt)
#pragma unroll
    for (int nt = 0; nt < 2; ++nt)
      ((f32x4*)red)[((w * 2 + mt) * 2 + nt) * 64 + lane] = acc[mt][nt];
  __syncthreads();

  {
    const int r2 = tid >> 5, b = tid & 31;
    const int mt = b >> 4, lg = (b & 15) >> 2, reg = b & 3;
    const size_t obase = (size_t)b * SS * VV + (size_t)(t + 1) * VV;
    u64 bestkey = 0ull;
#pragma unroll
    for (int q = 0; q < 2; ++q) {
      const int rho = r2 * 2 + q;
      const int v = blockIdx.x * 32 + rho;
      if (v < VV) {
        const int nt = rho >> 4, l15 = rho & 15;
        float val = fcb[v];
#pragma unroll
        for (int w2 = 0; w2 < 8; ++w2)
          val += red[(((w2 * 2 + mt) * 2 + nt) * 64 + lg * 16 + l15) * 4 + reg];
        out[obase + v] = val;
        u64 key = ((u64)enc_f32(val) << 32) | (0xFFFFFFFFu - (unsigned)v);
        if (key > bestkey) bestkey = key;
      }
    }
    kred[r2][b] = bestkey;
  }
  __syncthreads();
#pragma unroll
  for (int m = 8; m >= 1; m >>= 1) {
    if ((tid >> 5) < m) {
      u64 o = kred[(tid >> 5) + m][tid & 31];
      if (o > kred[tid >> 5][tid & 31]) kred[tid >> 5][tid & 31] = o;
    }
    __syncthreads();
  }
  if ((tid >> 5) == 0) atomicMax(&winners[(t & 1) * 32 + (tid & 31)], kred[0][tid & 31]);
  if (blockIdx.x == 0 && (tid >> 5) == 1) winners[((t + 1) & 1) * 32 + (tid & 31)] = 0ull;
}

// ======================= round-7 fallback path (verbatim) ====================
#define DOT4A(acc, q, r)                                                      \
  acc = fmaf((q).x, (r).x, acc); acc = fmaf((q).y, (r).y, acc);               \
  acc = fmaf((q).z, (r).z, acc); acc = fmaf((q).w, (r).w, acc);
__device__ __forceinline__ int colof(int b) { return (b & 3) * 8 + (b >> 2); }

__global__ __launch_bounds__(256) void k_zero_v7(float* __restrict__ p, int n) {
  int i = blockIdx.x * 256 + threadIdx.x;
  if (i < n) p[i] = 0.0f;
}
__global__ __launch_bounds__(256) void k_out0_v7(float* __restrict__ out,
                                                 u64* __restrict__ winners) {
  int i = blockIdx.x * 256 + threadIdx.x;
  if (i < BB * VV) out[(size_t)(i / VV) * SS * VV + (i % VV)] = 0.0f;
  if (i < 64) winners[i] = 0ull;
}
__global__ __launch_bounds__(256) void k_embed_v7(const int* __restrict__ x,
                                                  const float* __restrict__ emb,
                                                  float* __restrict__ xeT) {
  int i = blockIdx.x * 256 + threadIdx.x;
  int c = i & 3, col = (i >> 2) & 31, k4 = (i >> 7) & 127, s = i >> 14;
  int b = (col & 7) * 4 + (col >> 3);
  xeT[i] = emb[(size_t)x[b * SS + s] * EE + (k4 * 4 + c)];
}
__global__ __launch_bounds__(512, 2) void k_enc_step_v7(
    int t, const float* __restrict__ xeT, float* __restrict__ hfT,
    float* __restrict__ cfT, float* __restrict__ hbT, float* __restrict__ cbT,
    const float* __restrict__ Wih_f, const float* __restrict__ Whh_f,
    const float* __restrict__ b_f, const float* __restrict__ Wih_b,
    const float* __restrict__ Whh_b, const float* __restrict__ b_b) {
  __shared__ float wlds[2][32 * 33 * 4];
  __shared__ float alds[2][1024 * 4];
  const int tid = threadIdx.x;
  const int rg = tid & 7, bg = (tid >> 3) & 7, s = tid >> 6;
  const int dir = blockIdx.x >> 7, jb = (blockIdx.x & 127) * 8;
  const float* __restrict__ Wih = dir ? Wih_b : Wih_f;
  const float* __restrict__ Whh = dir ? Whh_b : Whh_f;
  const float* __restrict__ bias = dir ? b_b : b_f;
  float* hT = dir ? hbT : hfT;
  float* cT = dir ? cbT : cfT;
  const int sstep = dir ? (SS - 1 - t) : t;
  const int pin = t & 1;
  const float4* __restrict__ hin4 = (const float4*)(hT + pin * (HH * BB));
  const float4* __restrict__ xs4 = (const float4*)(xeT + (size_t)sstep * EE * BB);
  float* __restrict__ hout = hT + (pin ^ 1) * (HH * BB);
  const int NC = 12;
  auto wsrc = [&](int cc, int idx) -> float4 {
    int lrow = idx >> 5, k4 = idx & 31;
    int grow = (lrow >> 3) * HH + jb + (lrow & 7);
    return (cc < 8) ? ((const float4*)(Whh + (size_t)grow * HH))[cc * 32 + k4]
                    : ((const float4*)(Wih + (size_t)grow * EE))[(cc - 8) * 32 + k4];
  };
  auto asrc = [&](int cc, int idx) -> float4 {
    return (cc < 8) ? hin4[cc * 1024 + idx] : xs4[(cc - 8) * 1024 + idx];
  };
  auto wdst = [&](int buf, int idx) -> float4* {
    return (float4*)&wlds[buf][((idx >> 5) * 33 + (idx & 31)) * 4];
  };
  {
    float4 w0 = wsrc(0, tid), w1 = wsrc(0, 512 + tid);
    float4 a0 = asrc(0, tid), a1 = asrc(0, 512 + tid);
    *wdst(0, tid) = w0; *wdst(0, 512 + tid) = w1;
    ((float4*)alds[0])[tid] = a0; ((float4*)alds[0])[512 + tid] = a1;
  }
  __syncthreads();
  float acc[4][4];
#pragma unroll
  for (int i = 0; i < 4; ++i)
#pragma unroll
    for (int j = 0; j < 4; ++j) acc[i][j] = 0.0f;
  for (int cc = 0; cc < NC; ++cc) {
    const int cb = cc & 1;
    float4 pw0, pw1, pa0, pa1;
    const bool pref = (cc + 1 < NC);
    if (pref) {
      pw0 = wsrc(cc + 1, tid); pw1 = wsrc(cc + 1, 512 + tid);
      pa0 = asrc(cc + 1, tid); pa1 = asrc(cc + 1, 512 + tid);
    }
    const float4* __restrict__ ap = (const float4*)alds[cb];
    const float4* __restrict__ wp = (const float4*)wlds[cb];
#pragma unroll
    for (int sub = 0; sub < 4; ++sub) {
      const int k4 = sub * 8 + s;
      float4 av[4], wv[4];
#pragma unroll
      for (int j = 0; j < 4; ++j) av[j] = ap[k4 * 32 + j * 8 + bg];
#pragma unroll
      for (int i = 0; i < 4; ++i) wv[i] = wp[(rg + 8 * i) * 33 + k4];
#pragma unroll
      for (int i = 0; i < 4; ++i)
#pragma unroll
        for (int j = 0; j < 4; ++j) { DOT4A(acc[i][j], wv[i], av[j]); }
    }
    if (pref) {
      *wdst(cb ^ 1, tid) = pw0; *wdst(cb ^ 1, 512 + tid) = pw1;
      ((float4*)alds[cb ^ 1])[tid] = pa0; ((float4*)alds[cb ^ 1])[512 + tid] = pa1;
    }
    __syncthreads();
  }
  float* red = &wlds[0][0];
#pragma unroll
  for (int i = 0; i < 4; ++i)
#pragma unroll
    for (int j = 0; j < 4; ++j)
      red[(s * 32 + (rg + 8 * i)) * 32 + (bg * 4 + j)] = acc[i][j];
  __syncthreads();
  if (tid < 256) {
    const int c = tid >> 5, b = tid & 31;
    float g4[4];
#pragma unroll
    for (int g = 0; g < 4; ++g) {
      float v = bias[g * HH + jb + c];
#pragma unroll
      for (int s2 = 0; s2 < 8; ++s2) v += red[(s2 * 32 + g * 8 + c) * 32 + b];
      g4[g] = v;
    }
    const int j = jb + c;
    const int idx = j * BB + b;
    float cv = fmaf(sigm(g4[1]), cT[idx], sigm(g4[0]) * tanhf(g4[2]));
    cT[idx] = cv;
    hout[(j >> 2) * 128 + colof(b) * 4 + (j & 3)] = sigm(g4[3]) * tanhf(cv);
  }
}
__global__ __launch_bounds__(256) void k_enc_bn_v7(
    const float* __restrict__ hfT, const float* __restrict__ hbT,
    const float* __restrict__ gamma, const float* __restrict__ beta,
    float* __restrict__ hdT) {
  const int d = blockIdx.x * 8 + (threadIdx.x >> 5);
  const int b = threadIdx.x & 31;
  const int dl = (d < HH) ? d : d - HH;
  const float* __restrict__ src = (d < HH) ? hfT : hbT;
  float v = src[(dl >> 2) * 128 + colof(b) * 4 + (dl & 3)];
  float sum = v;
  for (int m = 16; m >= 1; m >>= 1) sum += __shfl_xor(sum, m, 32);
  float mean = sum * (1.0f / BB);
  float dx = v - mean;
  float s2 = dx * dx;
  for (int m = 16; m >= 1; m >>= 1) s2 += __shfl_xor(s2, m, 32);
  float var = s2 * (1.0f / BB);
  float y = dx * (1.0f / sqrtf(var + 1e-5f)) * gamma[d] + beta[d];
  hdT[(d >> 2) * 128 + colof(b) * 4 + (d & 3)] = fmaxf(y, 0.0f);
}
__global__ __launch_bounds__(512, 2) void k_dec_gates_v7(
    int t, const int* __restrict__ x, const float* __restrict__ emb,
    float* __restrict__ hdT, float* __restrict__ cdT, float* __restrict__ outT,
    const float* __restrict__ Wih, const float* __restrict__ Whh,
    const float* __restrict__ bias, const float* __restrict__ gamma,
    const float* __restrict__ beta, const u64* __restrict__ winners) {
  __shared__ float wlds[2][32 * 33 * 4];
  __shared__ float alds[2][1024 * 4];
  __shared__ int stoks[32];
  const int tid = threadIdx.x;
  const int rg = tid & 7, bg = (tid >> 3) & 7, s = tid >> 6;
  const int jb = blockIdx.x * 8;
  const int pin = t & 1;
  const float4* __restrict__ hin4 = (const float4*)(hdT + pin * (DD * BB));
  float* __restrict__ hout = hdT + (pin ^ 1) * (DD * BB);
  if (tid < 32)
    stoks[tid] = (t == 0) ? x[tid * SS]
                          : (int)(0xFFFFFFFFu -
                                  (unsigned)(winners[((t - 1) & 1) * 32 + tid] & 0xFFFFFFFFull));
  const int NC = 20;
  auto wsrc = [&](int cc, int idx) -> float4 {
    int lrow = idx >> 5, k4 = idx & 31;
    int grow = (lrow >> 3) * DD + jb + (lrow & 7);
    return (cc < 16) ? ((const float4*)(Whh + (size_t)grow * DD))[cc * 32 + k4]
                     : ((const float4*)(Wih + (size_t)grow * EE))[(cc - 16) * 32 + k4];
  };
  auto asrc = [&](int cc, int idx) -> float4 {
    if (cc < 16) return hin4[cc * 1024 + idx];
    int col = idx & 31;
    int b = (col & 7) * 4 + (col >> 3);
    return ((const float4*)(emb + (size_t)stoks[b] * EE))[(cc - 16) * 32 + (idx >> 5)];
  };
  auto wdst = [&](int buf, int idx) -> float4* {
    return (float4*)&wlds[buf][((idx >> 5) * 33 + (idx & 31)) * 4];
  };
  {
    float4 w0 = wsrc(0, tid), w1 = wsrc(0, 512 + tid);
    float4 a0 = asrc(0, tid), a1 = asrc(0, 512 + tid);
    *wdst(0, tid) = w0; *wdst(0, 512 + tid) = w1;
    ((float4*)alds[0])[tid] = a0; ((float4*)alds[0])[512 + tid] = a1;
  }
  __syncthreads();
  float acc[4][4];
#pragma unroll
  for (int i = 0; i < 4; ++i)
#pragma unroll
    for (int j = 0; j < 4; ++j) acc[i][j] = 0.0f;
  for (int cc = 0; cc < NC; ++cc) {
    const int cb = cc & 1;
    float4 pw0, pw1, pa0, pa1;
    const bool pref = (cc + 1 < NC);
    if (pref) {
      pw0 = wsrc(cc + 1, tid); pw1 = wsrc(cc + 1, 512 + tid);
      pa0 = asrc(cc + 1, tid); pa1 = asrc(cc + 1, 512 + tid);
    }
    const float4* __restrict__ ap = (const float4*)alds[cb];
    const float4* __restrict__ wp = (const float4*)wlds[cb];
#pragma unroll
    for (int sub = 0; sub < 4; ++sub) {
      const int k4 = sub * 8 + s;
      float4 av[4], wv[4];
#pragma unroll
      for (int j = 0; j < 4; ++j) av[j] = ap[k4 * 32 + j * 8 + bg];
#pragma unroll
      for (int i = 0; i < 4; ++i) wv[i] = wp[(rg + 8 * i) * 33 + k4];
#pragma unroll
      for (int i = 0; i < 4; ++i)
#pragma unroll
        for (int j = 0; j < 4; ++j) { DOT4A(acc[i][j], wv[i], av[j]); }
    }
    if (pref) {
      *wdst(cb ^ 1, tid) = pw0; *wdst(cb ^ 1, 512 + tid) = pw1;
      ((float4*)alds[cb ^ 1])[tid] = pa0; ((float4*)alds[cb ^ 1])[512 + tid] = pa1;
    }
    __syncthreads();
  }
  float* red = &wlds[0][0];
#pragma unroll
  for (int i = 0; i < 4; ++i)
#pragma unroll
    for (int j = 0; j < 4; ++j)
      red[(s * 32 + (rg + 8 * i)) * 32 + (bg * 4 + j)] = acc[i][j];
  __syncthreads();
  if (tid < 256) {
    const int c = tid >> 5, b = tid & 31;
    float g4[4];
#pragma unroll
    for (int g = 0; g < 4; ++g) {
      float v = bias[g * DD + jb + c];
#pragma unroll
      for (int s2 = 0; s2 < 8; ++s2) v += red[(s2 * 32 + g * 8 + c) * 32 + b];
      g4[g] = v;
    }
    const int j = jb + c;
    const int idx = j * BB + b;
    float cv = fmaf(sigm(g4[1]), cdT[idx], sigm(g4[0]) * tanhf(g4[2]));
    cdT[idx] = cv;
    float h = sigm(g4[3]) * tanhf(cv);
    hout[(j >> 2) * 128 + colof(b) * 4 + (j & 3)] = h;
    float sum = h;
    for (int m = 16; m >= 1; m >>= 1) sum += __shfl_xor(sum, m, 32);
    float mean = sum * (1.0f / BB);
    float dx = h - mean;
    float s2v = dx * dx;
    for (int m = 16; m >= 1; m >>= 1) s2v += __shfl_xor(s2v, m, 32);
    float var = s2v * (1.0f / BB);
    float y = dx * (1.0f / sqrtf(var + 1e-5f)) * gamma[j] + beta[j];
    outT[(j >> 2) * 128 + colof(b) * 4 + (j & 3)] = fmaxf(y, 0.0f);
  }
}
__global__ __launch_bounds__(512, 2) void k_fc_v7(
    int t, const float* __restrict__ outT, const float* __restrict__ fcW,
    const float* __restrict__ fcb, float* __restrict__ out,
    u64* __restrict__ winners) {
  __shared__ float wlds[2][40 * 33 * 4];
  __shared__ float alds[2][1024 * 4];
  __shared__ u64 kred[16][32];
  const int tid = threadIdx.x;
  const int rg = tid & 7, bg = (tid >> 3) & 7, s = tid >> 6;
  const int vb = blockIdx.x * 40;
  const float4* __restrict__ xa4 = (const float4*)outT;
  const int NC = 16;
  auto wsrc = [&](int cc, int idx) -> float4 {
    int lrow = idx >> 5, k4 = idx & 31;
    return ((const float4*)(fcW + (size_t)(vb + lrow) * DD))[cc * 32 + k4];
  };
  auto wdst = [&](int buf, int idx) -> float4* {
    return (float4*)&wlds[buf][((idx >> 5) * 33 + (idx & 31)) * 4];
  };
  {
    float4 w0 = wsrc(0, tid), w1 = wsrc(0, 512 + tid);
    float4 a0 = xa4[tid], a1 = xa4[512 + tid];
    *wdst(0, tid) = w0; *wdst(0, 512 + tid) = w1;
    if (tid < 256) *wdst(0, 1024 + tid) = wsrc(0, 1024 + tid);
    ((float4*)alds[0])[tid] = a0; ((float4*)alds[0])[512 + tid] = a1;
  }
  __syncthreads();
  float acc[5][4];
#pragma unroll
  for (int i = 0; i < 5; ++i)
#pragma unroll
    for (int j = 0; j < 4; ++j) acc[i][j] = 0.0f;
  for (int cc = 0; cc < NC; ++cc) {
    const int cb = cc & 1;
    float4 pw0, pw1, pw2, pa0, pa1;
    const bool pref = (cc + 1 < NC);
    if (pref) {
      pw0 = wsrc(cc + 1, tid); pw1 = wsrc(cc + 1, 512 + tid);
      if (tid < 256) pw2 = wsrc(cc + 1, 1024 + tid);
      pa0 = xa4[(cc + 1) * 1024 + tid];
      pa1 = xa4[(cc + 1) * 1024 + 512 + tid];
    }
    const float4* __restrict__ ap = (const float4*)alds[cb];
    const float4* __restrict__ wp = (const float4*)wlds[cb];
#pragma unroll
    for (int sub = 0; sub < 4; ++sub) {
      const int k4 = sub * 8 + s;
      float4 av[4], wv[5];
#pragma unroll
      for (int j = 0; j < 4; ++j) av[j] = ap[k4 * 32 + j * 8 + bg];
#pragma unroll
      for (int i = 0; i < 5; ++i) wv[i] = wp[(rg + 8 * i) * 33 + k4];
#pragma unroll
      for (int i = 0; i < 5; ++i)
#pragma unroll
        for (int j = 0; j < 4; ++j) { DOT4A(acc[i][j], wv[i], av[j]); }
    }
    if (pref) {
      *wdst(cb ^ 1, tid) = pw0; *wdst(cb ^ 1, 512 + tid) = pw1;
      if (tid < 256) *wdst(cb ^ 1, 1024 + tid) = pw2;
      ((float4*)alds[cb ^ 1])[tid] = pa0; ((float4*)alds[cb ^ 1])[512 + tid] = pa1;
    }
    __syncthreads();
  }
  float* red = &wlds[0][0];
#pragma unroll
  for (int i = 0; i < 5; ++i)
#pragma unroll
    for (int j = 0; j < 4; ++j)
      red[(s * 40 + (rg + 8 * i)) * 32 + (bg * 4 + j)] = acc[i][j];
  __syncthreads();
  const int r = tid >> 5, b = tid & 31;
  const size_t obase = (size_t)b * SS * VV + (size_t)(t + 1) * VV;
  u64 bestkey = 0ull;
  for (int lrow = r; lrow < 40; lrow += 16) {
    const int v = vb + lrow;
    float val = fcb[v];
#pragma unroll
    for (int s2 = 0; s2 < 8; ++s2) val += red[(s2 * 40 + lrow) * 32 + b];
    out[obase + v] = val;
    u64 key = ((u64)enc_f32(val) << 32) | (0xFFFFFFFFu - (unsigned)v);
    if (key > bestkey) bestkey = key;
  }
  kred[r][b] = bestkey;
  __syncthreads();
#pragma unroll
  for (int m = 8; m >= 1; m >>= 1) {
    if (r < m) {
      u64 o = kred[r + m][b];
      if (o > kred[r][b]) kred[r][b] = o;
    }
    __syncthreads();
  }
  if (r == 0) atomicMax(&winners[(t & 1) * 32 + b], kred[0][b]);
  if (blockIdx.x == 0 && r == 1) winners[((t + 1) & 1) * 32 + b] = 0ull;
}

// ============================ launch =========================================
extern "C" void kernel_launch(void* const* d_in, const int* in_sizes, int n_in,
                              void* d_out, int out_size, void* d_ws, size_t ws_size,
                              hipStream_t stream) {
  const int*   x         = (const int*)d_in[0];
  const float* emb       = (const float*)d_in[1];
  const float* Wih_f     = (const float*)d_in[2];
  const float* Whh_f     = (const float*)d_in[3];
  const float* b_f       = (const float*)d_in[4];
  const float* Wih_b     = (const float*)d_in[5];
  const float* Whh_b     = (const float*)d_in[6];
  const float* b_b       = (const float*)d_in[7];
  const float* Wih_d     = (const float*)d_in[8];
  const float* Whh_d     = (const float*)d_in[9];
  const float* b_d       = (const float*)d_in[10];
  const float* enc_gamma = (const float*)d_in[11];
  const float* enc_beta  = (const float*)d_in[12];
  const float* dec_gamma = (const float*)d_in[13];
  const float* dec_beta  = (const float*)d_in[14];
  const float* fcW       = (const float*)d_in[15];
  const float* fcb       = (const float*)d_in[16];
  float* out = (float*)d_out;

  // ---- MFMA-path ws layout (ushort regions first, 16B-aligned) ----
  const size_t WDEC_U = (size_t)80 * 2 * 512 * 512;   // 41,943,040
  const size_t WFC_U  = (size_t)64 * 2 * 626 * 512;   // 41,025,536
  const size_t WENC_U = (size_t)48 * 2 * 512 * 512;   // 25,165,824
  const size_t HDP_U  = (size_t)64 * 2 * 2 * 512;     // 131,072 per parity
  const size_t HEP_U  = (size_t)32 * 2 * 2 * 512;     // 65,536 per buffer
  const size_t need = (WDEC_U + WFC_U + WENC_U + 2 * HDP_U + HDP_U + 4 * HEP_U) * 2 +
                      (size_t)(HH * BB * 2 + DD * BB + HH * BB * 2) * 4 + 512;

  if (ws_size >= need + 1024) {
    ushort_t* us = (ushort_t*)d_ws;
    ushort_t* Wpdec = us;               us += WDEC_U;
    ushort_t* Wpfc  = us;               us += WFC_U;
    ushort_t* Wpenc = us;               us += WENC_U;
    ushort_t* hdp   = us;               us += 2 * HDP_U;   // decoder h ping-pong
    ushort_t* outp  = us;               us += HDP_U;       // fc input
    ushort_t* hencp = us;               us += 4 * HEP_U;   // enc h [dir][pp]
    float* f = (float*)us;
    float* cT2  = f;  f += HH * BB * 2;                     // cfT | cbT
    float* cdT  = f;  f += DD * BB;
    float* hT2  = f;  f += HH * BB * 2;                     // hfT | hbT (fp32)
    u64* winners = (u64*)f;

    // one-time packs (independent)
    k_pack_wdec<<<10240, 256, 0, stream>>>(Whh_d, Wih_d, Wpdec);
    k_pack_wfc<<<10016, 256, 0, stream>>>(fcW, Wpfc);
    k_pack_wenc<<<6144, 256, 0, stream>>>(Whh_f, Wih_f, Whh_b, Wih_b, Wpenc);
    // zero packed-act buffers + fp32 states + winners (contiguous from hdp)
    {
      size_t zbytes = (2 * HDP_U + HDP_U + 4 * HEP_U) * 2 +
                      (size_t)(HH * BB * 2 + DD * BB + HH * BB * 2) * 4 + 512;
      int zn = (int)(zbytes / 4);
      k_zero32<<<(zn + 255) / 256, 256, 0, stream>>>((unsigned*)hdp, zn);
    }
    k_out0<<<(BB * VV + 255) / 256, 256, 0, stream>>>(out);

    for (int t = 0; t < SS; ++t)
      k_enc_mfma<<<256, 512, 0, stream>>>(t, x, emb, Wpenc, hencp, cT2, hT2, b_f, b_b);

    k_bn_handoff<<<DD / 8, 256, 0, stream>>>(hT2, enc_gamma, enc_beta, hdp);

    for (int t = 0; t < SS - 1; ++t) {
      k_dec_mfma<<<256, 512, 0, stream>>>(t, x, emb, Wpdec, hdp, cdT, outp,
                                          b_d, dec_gamma, dec_beta, winners);
      k_fc_mfma<<<313, 512, 0, stream>>>(t, outp, Wpfc, fcb, out, winners);
    }
    return;
  }

  // ---------------- fallback: round-7 path ----------------
  float* ws = (float*)d_ws;
  size_t off = 0;
  float* xeT = ws + off; off += (size_t)SS * EE * BB;
  float* hfT = ws + off; off += 2 * HH * BB;
  float* hbT = ws + off; off += 2 * HH * BB;
  float* cfT = ws + off; off += HH * BB;
  float* cbT = ws + off; off += HH * BB;
  float* hdT = ws + off; off += 2 * DD * BB;
  float* cdT = ws + off; off += DD * BB;
  float* outT = ws + off; off += DD * BB;
  u64* winners = (u64*)(ws + off); off += 128;

  const int nz = 2 * HH * BB * 2 + HH * BB * 2 + 2 * DD * BB + DD * BB;
  k_zero_v7<<<(nz + 255) / 256, 256, 0, stream>>>(hfT, nz);
  k_out0_v7<<<(BB * VV + 255) / 256, 256, 0, stream>>>(out, winners);
  k_embed_v7<<<(SS * EE * BB) / 256, 256, 0, stream>>>(x, emb, xeT);

  for (int t = 0; t < SS; ++t)
    k_enc_step_v7<<<256, 512, 0, stream>>>(t, xeT, hfT, cfT, hbT, cbT,
                                           Wih_f, Whh_f, b_f, Wih_b, Whh_b, b_b);
  k_enc_bn_v7<<<DD / 8, 256, 0, stream>>>(hfT, hbT, enc_gamma, enc_beta, hdT);
  for (int t = 0; t < SS - 1; ++t) {
    k_dec_gates_v7<<<DD / 8, 512, 0, stream>>>(t, x, emb, hdT, cdT, outT,
                                               Wih_d, Whh_d, b_d,
                                               dec_gamma, dec_beta, winners);
    k_fc_v7<<<VV / 40, 512, 0, stream>>>(t, outT, fcW, fcb, out, winners);
  }
}